// Round 7
// baseline (532.779 us; speedup 1.0000x reference)
//
#include <hip/hip_runtime.h>

#define N_NODES 8192
#define DEG     16
#define NEDGE   (N_NODES*DEG)
#define F       128
#define F3      384
#define RBF     20
#define NLAYER  3
#define NF      (N_NODES*F)
#define PI_F    3.14159265358979f
#define AGG_G   8      // nodes per k_agg block

typedef unsigned short u16;
typedef __bf16 bf16x8 __attribute__((ext_vector_type(8)));
typedef float  f32x4  __attribute__((ext_vector_type(4)));

__device__ __forceinline__ float bf2f(u16 u){ return __uint_as_float(((unsigned)u)<<16); }
__device__ __forceinline__ u16 f2bf(float f){
  unsigned x = __float_as_uint(f);
  unsigned r = (x + 0x7FFFu + ((x>>16)&1u)) >> 16;   // RNE
  return (u16)r;
}
__device__ __forceinline__ float lo_bf(unsigned u){ return __uint_as_float(u<<16); }
__device__ __forceinline__ float hi_bf(unsigned u){ return __uint_as_float(u & 0xFFFF0000u); }
__device__ __forceinline__ float silu_f(float x){ return x / (1.f + __expf(-x)); }
__device__ __forceinline__ float ldsrc(const void* src, int i, int bf){
  return bf ? bf2f(((const u16*)src)[i]) : ((const float*)src)[i];
}

// ------------------------------------------------------------ dtype detect
__global__ void k_detect(const u16* __restrict__ rd, int* __restrict__ flag){
  if (threadIdx.x == 0 && blockIdx.x == 0){
    int ok = 1;
    for (int i = 0; i < 128; i++){
      float v = bf2f(rd[2*i]);
      if (!(v > 0.01f && v < 4.0f)) { ok = 0; break; }
    }
    *flag = ok;   // 1 = inputs bf16, 0 = fp32
  }
}

// ------------------------------------------- split helper: [L][K][N] -> [L][N][K] hi/lo
__device__ __forceinline__ void splitw(const void* src, u16* bh, u16* bl,
                                       int i, int K, int Ncol, int bf){
  int kn = K*Ncol; int l = i/kn; int r = i - l*kn; int k = r/Ncol; int n = r - k*Ncol;
  float w = ldsrc(src, i, bf);
  u16 h = f2bf(w);
  size_t o = (size_t)l*kn + (size_t)n*K + k;
  bh[o] = h; bl[o] = f2bf(w - bf2f(h));
}

// -------------------------------------- one fused preamble kernel (all weights)
__global__ __launch_bounds__(256) void k_prep(
    const void* mb1, const void* mb2, const void* rb, const void* b1, const void* b2,
    const void* rw,  const void* mw1, const void* mw2, const void* w1, const void* w2,
    const void* Uw,  const void* Vw,
    float* c_mb1, float* c_mb2, float* c_rb, float* c_b1, float* c_b2, float* c_rw,
    u16* mw1h, u16* mw1l, u16* mw2h, u16* mw2l, u16* w1h, u16* w1l,
    u16* w2h, u16* w2l, u16* uvh, u16* uvl,
    const int* __restrict__ flag){
  int i = blockIdx.x*256 + threadIdx.x;
  int bf = *flag;
  const int S0=NLAYER*F, S1=NLAYER*F3, S2=NLAYER*F3, S3=NLAYER*F, S4=NLAYER*F3;
  const int S5=NLAYER*RBF*F3;
  const int S6=NLAYER*F*F, S7=NLAYER*F*F3, S8=NLAYER*2*F*F, S9=NLAYER*F*F3, S10=NLAYER*256*F;
  if (i < S0){ c_mb1[i]=ldsrc(mb1,i,bf); return; } i-=S0;
  if (i < S1){ c_mb2[i]=ldsrc(mb2,i,bf); return; } i-=S1;
  if (i < S2){ c_rb[i] =ldsrc(rb, i,bf); return; } i-=S2;
  if (i < S3){ c_b1[i] =ldsrc(b1, i,bf); return; } i-=S3;
  if (i < S4){ c_b2[i] =ldsrc(b2, i,bf); return; } i-=S4;
  if (i < S5){ c_rw[i] =ldsrc(rw, i,bf); return; } i-=S5;
  if (i < S6){ splitw(mw1, mw1h, mw1l, i, F,   F,  bf); return; } i-=S6;
  if (i < S7){ splitw(mw2, mw2h, mw2l, i, F,   F3, bf); return; } i-=S7;
  if (i < S8){ splitw(w1,  w1h,  w1l,  i, 2*F, F,  bf); return; } i-=S8;
  if (i < S9){ splitw(w2,  w2h,  w2l,  i, F,   F3, bf); return; } i-=S9;
  if (i < S10){
    int l=i/(256*F); int r=i-l*(256*F); int n=r>>7; int k=r&127;
    int si=(l*F+k)*F+(n&127);
    float w = ldsrc((n<128)?Uw:Vw, si, bf);
    u16 h=f2bf(w); uvh[i]=h; uvl[i]=f2bf(w-bf2f(h));
  }
}
#define PREP_TOTAL (NLAYER*(F+F3+F3+F+F3+RBF*F3+F*F+F*F3+2*F*F+F*F3+256*F))

// ---------------------------------------------------------------- init nodes
__global__ __launch_bounds__(256) void k_init(const int* __restrict__ atoms,
                                              const void* __restrict__ emb_raw,
                                              float* __restrict__ s,
                                              u16* __restrict__ s_h, u16* __restrict__ s_l,
                                              float* __restrict__ vA,
                                              u16* __restrict__ v_pk,
                                              const int* __restrict__ flag){
  int i = blockIdx.x*256 + threadIdx.x;          // i < NF
  int bf = *flag;
  int n = i >> 7, f = i & 127;
  float sv = ldsrc(emb_raw, atoms[n]*F + f, bf);
  s[i] = sv;
  u16 hb = f2bf(sv); s_h[i] = hb; s_l[i] = f2bf(sv - bf2f(hb));
  vA[i] = 0.f; vA[NF+i] = 0.f; vA[2*NF+i] = 0.f;
  ((unsigned*)v_pk)[i] = 0;  v_pk[2*(size_t)NF + i] = 0;
}

// ------------------------------------------------ split-bf16 MFMA GEMM
// C = A @ B (+bias); A pre-split bf16 hi/lo planes [M][K]; B pre-split/transposed [N][K].
// flags: 1=silu, 2=write f32 C, 4=write packed phi to P1, 16=write split planes P1/P2.
__global__ __launch_bounds__(256) void k_mgemm(const u16* __restrict__ Ah_g,
                                               const u16* __restrict__ Al_g,
                                               const u16* __restrict__ Bh_g,
                                               const u16* __restrict__ Bl_g,
                                               const float* __restrict__ bias,
                                               float* __restrict__ C,
                                               u16* __restrict__ P1,
                                               u16* __restrict__ P2,
                                               int M, int Ncol, int K, int flags){
  __shared__ u16 Ah[64*40], Al[64*40], Bh[64*40], Bl[64*40];   // 20 KB
  int t = threadIdx.x;
  int row0 = blockIdx.y<<6, col0 = blockIdx.x<<6;
  int sr = t>>2, sc = (t&3)<<3;
  const u16* Agh = Ah_g + (size_t)(row0+sr)*K + sc;
  const u16* Agl = Al_g + (size_t)(row0+sr)*K + sc;
  const u16* Bgh = Bh_g + (size_t)(col0+sr)*K + sc;
  const u16* Bgl = Bl_g + (size_t)(col0+sr)*K + sc;
  int lane = t&63, w = t>>6;
  int qr = (w>>1)<<5, qc = (w&1)<<5;
  int l15 = lane&15, q8 = (lane>>4)<<3;
  f32x4 acc[2][2];
  #pragma unroll
  for (int mt=0;mt<2;mt++)
    #pragma unroll
    for (int nt=0;nt<2;nt++){ acc[mt][nt][0]=0.f; acc[mt][nt][1]=0.f; acc[mt][nt][2]=0.f; acc[mt][nt][3]=0.f; }

  for (int k0=0;k0<K;k0+=32){
    *(uint4*)&Ah[sr*40+sc] = *(const uint4*)(Agh+k0);
    *(uint4*)&Al[sr*40+sc] = *(const uint4*)(Agl+k0);
    *(uint4*)&Bh[sr*40+sc] = *(const uint4*)(Bgh+k0);
    *(uint4*)&Bl[sr*40+sc] = *(const uint4*)(Bgl+k0);
    __syncthreads();

    bf16x8 a_h[2], a_l[2], b_h[2], b_l[2];
    #pragma unroll
    for (int mt=0;mt<2;mt++){
      int off = (qr+mt*16+l15)*40 + q8;
      a_h[mt] = *(const bf16x8*)&Ah[off];
      a_l[mt] = *(const bf16x8*)&Al[off];
    }
    #pragma unroll
    for (int nt=0;nt<2;nt++){
      int off = (qc+nt*16+l15)*40 + q8;
      b_h[nt] = *(const bf16x8*)&Bh[off];
      b_l[nt] = *(const bf16x8*)&Bl[off];
    }
    #pragma unroll
    for (int mt=0;mt<2;mt++)
      #pragma unroll
      for (int nt=0;nt<2;nt++){
        acc[mt][nt] = __builtin_amdgcn_mfma_f32_16x16x32_bf16(a_h[mt], b_h[nt], acc[mt][nt], 0,0,0);
        acc[mt][nt] = __builtin_amdgcn_mfma_f32_16x16x32_bf16(a_h[mt], b_l[nt], acc[mt][nt], 0,0,0);
        acc[mt][nt] = __builtin_amdgcn_mfma_f32_16x16x32_bf16(a_l[mt], b_h[nt], acc[mt][nt], 0,0,0);
      }
    __syncthreads();
  }

  int qrow = (lane>>4)<<2;
  #pragma unroll
  for (int mt=0;mt<2;mt++)
    #pragma unroll
    for (int nt=0;nt<2;nt++){
      int gcol = col0 + qc + nt*16 + l15;
      float b = bias ? bias[gcol] : 0.f;
      #pragma unroll
      for (int r=0;r<4;r++){
        int grow = row0 + qr + mt*16 + qrow + r;
        float val = acc[mt][nt][r] + b;
        if (flags & 1) val = silu_f(val);
        size_t o = (size_t)grow*Ncol + gcol;
        if (flags & 2) C[o] = val;
        if (flags & 16){
          u16 hb = f2bf(val);
          P1[o] = hb; P2[o] = f2bf(val - bf2f(hb));
        }
        if (flags & 4){
          u16 bb = f2bf(val);
          size_t rowo = (size_t)grow*F;
          if (gcol < F)        P1[(rowo + gcol)*2]       = bb;   // vv -> lo16
          else if (gcol < 2*F) P1[(rowo + gcol - F)*2+1] = bb;   // ss -> hi16
          else                 P1[2*(size_t)NF + rowo + gcol - 2*F] = bb; // vs
        }
      }
    }
}

// ------------------------------------------------- fused message aggregation
__global__ __launch_bounds__(256) void k_agg(const int* __restrict__ idx_j,
                                             const void* __restrict__ dist_raw,
                                             const void* __restrict__ dir_raw,
                                             const u16* __restrict__ phi_pk,
                                             const float* __restrict__ rw_g,
                                             const float* __restrict__ rb_g,
                                             const u16* __restrict__ v_pk,
                                             const float* __restrict__ v_in,
                                             float* __restrict__ v_out,
                                             u16* __restrict__ vo_h,
                                             u16* __restrict__ vo_l,
                                             float* __restrict__ s,
                                             u16* __restrict__ s_h,
                                             u16* __restrict__ s_l,
                                             const int* __restrict__ flag){
  __shared__ float ed[2*DEG*24];    // per edge: 20 rbf*cut, cut, dir0..2
  __shared__ int   jl[2*DEG];
  int t = threadIdx.x;
  int bf = *flag;
  int half = t >> 7, f = t & 127;

  float rwf[RBF], rws[RBF], rwv[RBF];
  #pragma unroll
  for (int r=0;r<RBF;r++){
    rwf[r] = rw_g[r*F3 + f];
    rws[r] = rw_g[r*F3 + F + f];
    rwv[r] = rw_g[r*F3 + 2*F + f];
  }
  float rb0 = rb_g[f], rb1 = rb_g[F+f], rb2 = rb_g[2*F+f];

  const unsigned* phiA = (const unsigned*)phi_pk;
  const u16*      phiB = phi_pk + 2*(size_t)NF;
  const unsigned* vpA  = (const unsigned*)v_pk;
  const u16*      vpB  = v_pk + 2*(size_t)NF;

  int n0 = blockIdx.x * AGG_G;
  for (int p=0;p<AGG_G/2;p++){
    int nA = n0 + 2*p;
    __syncthreads();
    for (int i=t;i<2*DEG*24;i+=256){
      int el = i/24, q = i - el*24;
      int e = nA*DEG + el;
      float val;
      if (q <= 20){
        float d = ldsrc(dist_raw, e, bf);
        float cut = 0.5f*(cosf(PI_F*d*(1.f/3.f)) + 1.0f);
        if (q < 20) val = sinf((q+1)*PI_F*d*(1.f/3.f)) * cut / d;
        else        val = cut;
      } else {
        val = ldsrc(dir_raw, e*3 + (q-21), bf);
      }
      ed[i] = val;
    }
    if (t < 2*DEG) jl[t] = idx_j[nA*DEG + t];
    __syncthreads();

    int n = nA + half;
    const float* edh = ed + half*DEG*24;
    const int*   jlh = jl + half*DEG;
    float ds=0.f, dv0=0.f, dv1=0.f, dv2=0.f;

    int j0 = jlh[0];
    unsigned pa = phiA[(size_t)j0*F + f];
    u16      pb = phiB[(size_t)j0*F + f];
    unsigned va = vpA [(size_t)j0*F + f];
    u16      vb = vpB [(size_t)j0*F + f];
    for (int el=0;el<DEG;el++){
      unsigned cpa=pa; u16 cpb=pb; unsigned cva=va; u16 cvb=vb;
      if (el+1 < DEG){
        int j1 = jlh[el+1];
        pa = phiA[(size_t)j1*F + f];
        pb = phiB[(size_t)j1*F + f];
        va = vpA [(size_t)j1*F + f];
        vb = vpB [(size_t)j1*F + f];
      }
      const float4* e4 = (const float4*)&edh[el*24];
      float4 c0 = e4[0], c1 = e4[1], c2 = e4[2], c3 = e4[3], c4 = e4[4], c5 = e4[5];
      float cw = c5.x;
      float Wvv = cw*rb0, Wss = cw*rb1, Wvs = cw*rb2;
      float rc[RBF] = {c0.x,c0.y,c0.z,c0.w, c1.x,c1.y,c1.z,c1.w,
                       c2.x,c2.y,c2.z,c2.w, c3.x,c3.y,c3.z,c3.w,
                       c4.x,c4.y,c4.z,c4.w};
      #pragma unroll
      for (int r=0;r<RBF;r++){
        Wvv += rc[r]*rwf[r];
        Wss += rc[r]*rws[r];
        Wvs += rc[r]*rwv[r];
      }
      float pvv = Wvv*lo_bf(cpa), pss = Wss*hi_bf(cpa), pvs = Wvs*bf2f(cpb);
      ds += pss;
      dv0 += lo_bf(cva)*pvv + pvs*c5.y;
      dv1 += hi_bf(cva)*pvv + pvs*c5.z;
      dv2 += bf2f(cvb)*pvv + pvs*c5.w;
    }
    size_t i = (size_t)n*F + f;
    const float inv = 1.f/DEG;
    float sv = s[i] + ds*inv;
    s[i] = sv;
    { u16 hb = f2bf(sv); s_h[i] = hb; s_l[i] = f2bf(sv - bf2f(hb)); }
    float o0 = v_in[i]      + dv0*inv;
    float o1 = v_in[NF+i]   + dv1*inv;
    float o2 = v_in[2*NF+i] + dv2*inv;
    v_out[i] = o0; v_out[NF+i] = o1; v_out[2*NF+i] = o2;
    u16 h0=f2bf(o0), h1=f2bf(o1), h2=f2bf(o2);
    vo_h[i]=h0; vo_h[NF+i]=h1; vo_h[2*NF+i]=h2;
    vo_l[i]=f2bf(o0-bf2f(h0)); vo_l[NF+i]=f2bf(o1-bf2f(h1)); vo_l[2*NF+i]=f2bf(o2-bf2f(h2));
  }
}

// ---------------------------------- dot / norm; builds split a_in = [vnorm | s]
__global__ __launch_bounds__(256) void k_dotnorm(const float* __restrict__ UVv,
                                                 const float* __restrict__ s,
                                                 float* __restrict__ dot,
                                                 u16* __restrict__ ai_h,
                                                 u16* __restrict__ ai_l){
  int i = blockIdx.x*256 + threadIdx.x;  // < NF
  int n = i >> 7, f = i & 127;
  size_t b = (size_t)n*256 + f;
  float u0=UVv[b],        w0=UVv[b+128];
  float u1=UVv[2*NF+b],   w1=UVv[2*NF+b+128];
  float u2=UVv[4*NF+b],   w2=UVv[4*NF+b+128];
  dot[i] = u0*w0 + u1*w1 + u2*w2;
  float vn = sqrtf(w0*w0 + w1*w1 + w2*w2);
  float sv = s[i];
  u16 h0 = f2bf(vn), h1 = f2bf(sv);
  ai_h[b] = h0;     ai_l[b] = f2bf(vn - bf2f(h0));
  ai_h[b+128] = h1; ai_l[b+128] = f2bf(sv - bf2f(h1));
}

// ------------------------------------------------------------- apply update
__global__ __launch_bounds__(256) void k_apply(const float* __restrict__ a,
                                               const float* __restrict__ dot,
                                               const float* __restrict__ UVv,
                                               float* __restrict__ s,
                                               u16* __restrict__ s_h,
                                               u16* __restrict__ s_l,
                                               float* __restrict__ v,
                                               u16* __restrict__ v_pk){
  int i = blockIdx.x*256 + threadIdx.x;
  int n = i >> 7, f = i & 127;
  const float* row = a + (size_t)n*F3;
  float avv = row[f], asv = row[F+f], ass = row[2*F+f];
  float sv = s[i] + ass + asv*dot[i];
  s[i] = sv;
  { u16 hb = f2bf(sv); s_h[i] = hb; s_l[i] = f2bf(sv - bf2f(hb)); }
  size_t b = (size_t)n*256 + f;
  float nv0 = v[i]      + UVv[b]*avv;
  float nv1 = v[NF+i]   + UVv[2*NF+b]*avv;
  float nv2 = v[2*NF+i] + UVv[4*NF+b]*avv;
  v[i] = nv0; v[NF+i] = nv1; v[2*NF+i] = nv2;
  ((unsigned*)v_pk)[i] = (unsigned)f2bf(nv0) | ((unsigned)f2bf(nv1)<<16);
  v_pk[2*(size_t)NF + i] = f2bf(nv2);
}

// ----------------------------------------------------- output (FP32 output)
__global__ __launch_bounds__(256) void k_pack(const float* __restrict__ s,
                                              const float* __restrict__ v,
                                              float* __restrict__ out){
  int i = blockIdx.x*256 + threadIdx.x;   // i < NF
  out[i] = s[i];
  out[NF + (size_t)i*3 + 0] = v[i];
  out[NF + (size_t)i*3 + 1] = v[NF+i];
  out[NF + (size_t)i*3 + 2] = v[2*NF+i];
}

// ------------------------------------------------------------------ launch
extern "C" void kernel_launch(void* const* d_in, const int* in_sizes, int n_in,
                              void* d_out, int out_size, void* d_ws, size_t ws_size,
                              hipStream_t stream) {
  const int* atoms   = (const int*)d_in[0];
  const int* idxj    = (const int*)d_in[2];

  float* W = (float*)d_ws;
  size_t off = 16;
  int* flag = (int*)d_ws;
  #define ALLOCF(name, cnt) float* name = W+off; off += (((cnt)+63)&~(size_t)63)
  #define ALLOCU(name, cnt) u16* name = (u16*)(W+off); off += ((((cnt)+1)/2+63)&~(size_t)63)
  ALLOCF(c_mb1, NLAYER*F);
  ALLOCF(c_mb2, NLAYER*F3);
  ALLOCF(c_rb,  NLAYER*F3);
  ALLOCF(c_b1,  NLAYER*F);
  ALLOCF(c_b2,  NLAYER*F3);
  ALLOCF(c_rw,  NLAYER*RBF*F3);
  ALLOCU(w_mw1h, NLAYER*F*F);   ALLOCU(w_mw1l, NLAYER*F*F);
  ALLOCU(w_mw2h, NLAYER*F*F3);  ALLOCU(w_mw2l, NLAYER*F*F3);
  ALLOCU(w_uvh,  NLAYER*256*F); ALLOCU(w_uvl,  NLAYER*256*F);
  ALLOCU(w_w1h,  NLAYER*F*256); ALLOCU(w_w1l,  NLAYER*F*256);
  ALLOCU(w_w2h,  NLAYER*F*F3);  ALLOCU(w_w2l,  NLAYER*F*F3);
  ALLOCU(phi_pk, (size_t)3*NF);
  ALLOCU(v_pk,   (size_t)3*NF);
  ALLOCU(s_h,  NF); ALLOCU(s_l,  NF);
  ALLOCU(h_h,  NF); ALLOCU(h_l,  NF);
  ALLOCU(ai_h, (size_t)2*NF); ALLOCU(ai_l, (size_t)2*NF);
  ALLOCU(vo_h, (size_t)3*NF); ALLOCU(vo_l, (size_t)3*NF);
  ALLOCF(s,    NF);
  ALLOCF(vA,   (size_t)3*NF);
  ALLOCF(vB,   (size_t)3*NF);
  ALLOCF(UVv,  (size_t)6*NF);
  ALLOCF(dotb, NF);

  k_detect<<<1, 64, 0, stream>>>((const u16*)d_in[4], flag);
  k_prep<<<(PREP_TOTAL+255)/256, 256, 0, stream>>>(
      d_in[7], d_in[9], d_in[11], d_in[15], d_in[17],
      d_in[10], d_in[6], d_in[8], d_in[14], d_in[16],
      d_in[12], d_in[13],
      c_mb1, c_mb2, c_rb, c_b1, c_b2, c_rw,
      w_mw1h, w_mw1l, w_mw2h, w_mw2l, w_w1h, w_w1l,
      w_w2h, w_w2l, w_uvh, w_uvl, flag);

  k_init<<<NF/256, 256, 0, stream>>>(atoms, d_in[5], s, s_h, s_l, vA, v_pk, flag);

  for (int l=0; l<NLAYER; l++){
    float* vin  = (l & 1) ? vB : vA;
    float* vout = (l & 1) ? vA : vB;
    // ---- message block ----
    // h = silu(s@mw1+mb1), written as split planes
    k_mgemm<<<dim3(F/64, N_NODES/64), 256, 0, stream>>>(
        s_h, s_l, w_mw1h + (size_t)l*F*F, w_mw1l + (size_t)l*F*F,
        c_mb1 + (size_t)l*F, nullptr, h_h, h_l, N_NODES, F, F, 1|16);
    // phi = h@mw2+mb2, written packed bf16
    k_mgemm<<<dim3(F3/64, N_NODES/64), 256, 0, stream>>>(
        h_h, h_l, w_mw2h + (size_t)l*F*F3, w_mw2l + (size_t)l*F*F3,
        c_mb2 + (size_t)l*F3, nullptr, phi_pk, nullptr, N_NODES, F3, F, 4);
    k_agg<<<N_NODES/AGG_G, 256, 0, stream>>>(
        idxj, d_in[4], d_in[3], phi_pk,
        c_rw + (size_t)l*RBF*F3, c_rb + (size_t)l*F3,
        v_pk, vin, vout, vo_h, vo_l, s, s_h, s_l, flag);
    // ---- update block ----
    k_mgemm<<<dim3(256/64, 3*N_NODES/64), 256, 0, stream>>>(
        vo_h, vo_l, w_uvh + (size_t)l*256*F, w_uvl + (size_t)l*256*F,
        nullptr, UVv, nullptr, nullptr, 3*N_NODES, 256, F, 2);
    k_dotnorm<<<NF/256, 256, 0, stream>>>(UVv, s, dotb, ai_h, ai_l);
    k_mgemm<<<dim3(F/64, N_NODES/64), 256, 0, stream>>>(
        ai_h, ai_l, w_w1h + (size_t)l*F*256, w_w1l + (size_t)l*F*256,
        c_b1 + (size_t)l*F, nullptr, h_h, h_l, N_NODES, F, 2*F, 1|16);
    k_mgemm<<<dim3(F3/64, N_NODES/64), 256, 0, stream>>>(
        h_h, h_l, w_w2h + (size_t)l*F*F3, w_w2l + (size_t)l*F*F3,
        c_b2 + (size_t)l*F3, vin, nullptr, nullptr, N_NODES, F3, F, 2);
    k_apply<<<NF/256, 256, 0, stream>>>(vin, dotb, UVv, s, s_h, s_l, vout, v_pk);
  }

  k_pack<<<NF/256, 256, 0, stream>>>(s, vB, (float*)d_out);
}

// Round 9
// 445.722 us; speedup vs baseline: 1.1953x; 1.1953x over previous
//
#include <hip/hip_runtime.h>
#include <hip/hip_fp16.h>

#define N_NODES 8192
#define DEG     16
#define NEDGE   (N_NODES*DEG)
#define F       128
#define F3      384
#define RBF     20
#define NLAYER  3
#define NF      (N_NODES*F)
#define PI_F    3.14159265358979f
#define AGG_G   8      // nodes per k_agg block

typedef unsigned short u16;
typedef __bf16 bf16x8 __attribute__((ext_vector_type(8)));
typedef float  f32x4  __attribute__((ext_vector_type(4)));

__device__ __forceinline__ float bf2f(u16 u){ return __uint_as_float(((unsigned)u)<<16); }
__device__ __forceinline__ u16 f2bf(float f){
  unsigned x = __float_as_uint(f);
  unsigned r = (x + 0x7FFFu + ((x>>16)&1u)) >> 16;   // RNE
  return (u16)r;
}
__device__ __forceinline__ float lo_bf(unsigned u){ return __uint_as_float(u<<16); }
__device__ __forceinline__ float hi_bf(unsigned u){ return __uint_as_float(u & 0xFFFF0000u); }
__device__ __forceinline__ float silu_f(float x){ return x / (1.f + __expf(-x)); }
__device__ __forceinline__ float ldsrc(const void* src, int i, int bf){
  return bf ? bf2f(((const u16*)src)[i]) : ((const float*)src)[i];
}
__device__ __forceinline__ unsigned packh2(float a, float b){
  return (unsigned)__half_as_ushort(__float2half(a)) |
         ((unsigned)__half_as_ushort(__float2half(b)) << 16);
}
__device__ __forceinline__ __half2 u2h2(unsigned u){ return __builtin_bit_cast(__half2, u); }

// ------------------------------------------------------------ dtype detect
__global__ void k_detect(const u16* __restrict__ rd, int* __restrict__ flag){
  if (threadIdx.x == 0 && blockIdx.x == 0){
    int ok = 1;
    for (int i = 0; i < 128; i++){
      float v = bf2f(rd[2*i]);
      if (!(v > 0.01f && v < 4.0f)) { ok = 0; break; }
    }
    *flag = ok;   // 1 = inputs bf16, 0 = fp32
  }
}

// ------------------------------------------- split helper: [L][K][N] -> [L][N][K] hi/lo
__device__ __forceinline__ void splitw(const void* src, u16* bh, u16* bl,
                                       int i, int K, int Ncol, int bf){
  int kn = K*Ncol; int l = i/kn; int r = i - l*kn; int k = r/Ncol; int n = r - k*Ncol;
  float w = ldsrc(src, i, bf);
  u16 h = f2bf(w);
  size_t o = (size_t)l*kn + (size_t)n*K + k;
  bh[o] = h; bl[o] = f2bf(w - bf2f(h));
}

// -------------------------------------- one fused preamble kernel
__global__ __launch_bounds__(256) void k_prep(
    const void* mb1, const void* mb2, const void* b1, const void* b2,
    const void* rw,  const void* rb,
    const void* mw1, const void* mw2, const void* w1, const void* w2,
    const void* Uw,  const void* Vw,
    const void* dist, const void* dirv, const int* __restrict__ idxj,
    float* c_mb1, float* c_mb2, float* c_b1, float* c_b2,
    unsigned* rwp2,                 // [L][11][3F]
    u16* mw1h, u16* mw1l, u16* mw2h, u16* mw2l, u16* w1h, u16* w1l,
    u16* w2h, u16* w2l, u16* uvh, u16* uvl,
    uint4* edata,                   // [E][4]
    const int* __restrict__ flag){
  int i = blockIdx.x*256 + threadIdx.x;
  int bf = *flag;
  const int S0=NLAYER*F, S1=NLAYER*F3, S2=NLAYER*F, S3=NLAYER*F3;
  const int S4=NLAYER*11*F3;
  const int S5=NLAYER*F*F, S6=NLAYER*F*F3, S7=NLAYER*2*F*F, S8=NLAYER*F*F3, S9=NLAYER*256*F;
  if (i < S0){ c_mb1[i]=ldsrc(mb1,i,bf); return; } i-=S0;
  if (i < S1){ c_mb2[i]=ldsrc(mb2,i,bf); return; } i-=S1;
  if (i < S2){ c_b1[i] =ldsrc(b1, i,bf); return; } i-=S2;
  if (i < S3){ c_b2[i] =ldsrc(b2, i,bf); return; } i-=S3;
  if (i < S4){
    int l = i/(11*F3); int r = i - l*(11*F3); int r2 = r/F3; int col = r - r2*F3;
    float w0, w1v;
    if (r2 < 10){
      w0  = ldsrc(rw, (l*RBF + 2*r2  )*F3 + col, bf);
      w1v = ldsrc(rw, (l*RBF + 2*r2+1)*F3 + col, bf);
    } else {
      w0  = ldsrc(rb, l*F3 + col, bf);
      w1v = 0.f;
    }
    rwp2[i] = packh2(w0, w1v);
    return;
  } i-=S4;
  if (i < S5){ splitw(mw1, mw1h, mw1l, i, F,   F,  bf); return; } i-=S5;
  if (i < S6){ splitw(mw2, mw2h, mw2l, i, F,   F3, bf); return; } i-=S6;
  if (i < S7){ splitw(w1,  w1h,  w1l,  i, 2*F, F,  bf); return; } i-=S7;
  if (i < S8){ splitw(w2,  w2h,  w2l,  i, F,   F3, bf); return; } i-=S8;
  if (i < S9){
    int l=i/(256*F); int r=i-l*(256*F); int n=r>>7; int k=r&127;
    int si=(l*F+k)*F+(n&127);
    float w = ldsrc((n<128)?Uw:Vw, si, bf);
    u16 h=f2bf(w); uvh[i]=h; uvl[i]=f2bf(w-bf2f(h));
    return;
  } i-=S9;
  if (i < NEDGE){
    int e = i;
    float d = ldsrc(dist, e, bf);
    float cut = 0.5f*(cosf(PI_F*d*(1.f/3.f)) + 1.0f);
    float ic = cut/d;
    unsigned o[16];
    #pragma unroll
    for (int r2=0;r2<10;r2++){
      float s0 = sinf((2*r2+1)*PI_F*d*(1.f/3.f))*ic;
      float s1 = sinf((2*r2+2)*PI_F*d*(1.f/3.f))*ic;
      o[r2] = packh2(s0, s1);
    }
    o[10] = packh2(cut, 0.f);
    o[11] = __float_as_uint(ldsrc(dirv, e*3+0, bf));
    o[12] = __float_as_uint(ldsrc(dirv, e*3+1, bf));
    o[13] = __float_as_uint(ldsrc(dirv, e*3+2, bf));
    o[14] = (unsigned)idxj[e];
    o[15] = 0;
    uint4* dst = edata + (size_t)e*4;
    dst[0] = make_uint4(o[0],o[1],o[2],o[3]);
    dst[1] = make_uint4(o[4],o[5],o[6],o[7]);
    dst[2] = make_uint4(o[8],o[9],o[10],o[11]);
    dst[3] = make_uint4(o[12],o[13],o[14],o[15]);
  }
}
#define PREP_TOTAL (NLAYER*(F+F3+F+F3+11*F3+F*F+F*F3+2*F*F+F*F3+256*F) + NEDGE)

// ---------------------------------------------------------------- init nodes
__global__ __launch_bounds__(256) void k_init(const int* __restrict__ atoms,
                                              const void* __restrict__ emb_raw,
                                              float* __restrict__ s,
                                              u16* __restrict__ s_h, u16* __restrict__ s_l,
                                              float* __restrict__ vA,
                                              u16* __restrict__ v_pk,
                                              const int* __restrict__ flag){
  int i = blockIdx.x*256 + threadIdx.x;          // i < NF
  int bf = *flag;
  int n = i >> 7, f = i & 127;
  float sv = ldsrc(emb_raw, atoms[n]*F + f, bf);
  s[i] = sv;
  u16 hb = f2bf(sv); s_h[i] = hb; s_l[i] = f2bf(sv - bf2f(hb));
  vA[i] = 0.f; vA[NF+i] = 0.f; vA[2*NF+i] = 0.f;
  ((unsigned*)v_pk)[i] = 0;  v_pk[2*(size_t)NF + i] = 0;
}

// ------------------------------------------------ split-bf16 MFMA GEMM
// flags: 1=silu, 2=write f32 C, 4=write packed phi to P1, 16=write split planes P1/P2.
__global__ __launch_bounds__(256) void k_mgemm(const u16* __restrict__ Ah_g,
                                               const u16* __restrict__ Al_g,
                                               const u16* __restrict__ Bh_g,
                                               const u16* __restrict__ Bl_g,
                                               const float* __restrict__ bias,
                                               float* __restrict__ C,
                                               u16* __restrict__ P1,
                                               u16* __restrict__ P2,
                                               int M, int Ncol, int K, int flags){
  __shared__ u16 Ah[64*40], Al[64*40], Bh[64*40], Bl[64*40];   // 20 KB
  int t = threadIdx.x;
  int row0 = blockIdx.y<<6, col0 = blockIdx.x<<6;
  int sr = t>>2, sc = (t&3)<<3;
  const u16* Agh = Ah_g + (size_t)(row0+sr)*K + sc;
  const u16* Agl = Al_g + (size_t)(row0+sr)*K + sc;
  const u16* Bgh = Bh_g + (size_t)(col0+sr)*K + sc;
  const u16* Bgl = Bl_g + (size_t)(col0+sr)*K + sc;
  int lane = t&63, w = t>>6;
  int qr = (w>>1)<<5, qc = (w&1)<<5;
  int l15 = lane&15, q8 = (lane>>4)<<3;
  f32x4 acc[2][2];
  #pragma unroll
  for (int mt=0;mt<2;mt++)
    #pragma unroll
    for (int nt=0;nt<2;nt++){ acc[mt][nt][0]=0.f; acc[mt][nt][1]=0.f; acc[mt][nt][2]=0.f; acc[mt][nt][3]=0.f; }

  for (int k0=0;k0<K;k0+=32){
    *(uint4*)&Ah[sr*40+sc] = *(const uint4*)(Agh+k0);
    *(uint4*)&Al[sr*40+sc] = *(const uint4*)(Agl+k0);
    *(uint4*)&Bh[sr*40+sc] = *(const uint4*)(Bgh+k0);
    *(uint4*)&Bl[sr*40+sc] = *(const uint4*)(Bgl+k0);
    __syncthreads();

    bf16x8 a_h[2], a_l[2], b_h[2], b_l[2];
    #pragma unroll
    for (int mt=0;mt<2;mt++){
      int off = (qr+mt*16+l15)*40 + q8;
      a_h[mt] = *(const bf16x8*)&Ah[off];
      a_l[mt] = *(const bf16x8*)&Al[off];
    }
    #pragma unroll
    for (int nt=0;nt<2;nt++){
      int off = (qc+nt*16+l15)*40 + q8;
      b_h[nt] = *(const bf16x8*)&Bh[off];
      b_l[nt] = *(const bf16x8*)&Bl[off];
    }
    #pragma unroll
    for (int mt=0;mt<2;mt++)
      #pragma unroll
      for (int nt=0;nt<2;nt++){
        acc[mt][nt] = __builtin_amdgcn_mfma_f32_16x16x32_bf16(a_h[mt], b_h[nt], acc[mt][nt], 0,0,0);
        acc[mt][nt] = __builtin_amdgcn_mfma_f32_16x16x32_bf16(a_h[mt], b_l[nt], acc[mt][nt], 0,0,0);
        acc[mt][nt] = __builtin_amdgcn_mfma_f32_16x16x32_bf16(a_l[mt], b_h[nt], acc[mt][nt], 0,0,0);
      }
    __syncthreads();
  }

  int qrow = (lane>>4)<<2;
  #pragma unroll
  for (int mt=0;mt<2;mt++)
    #pragma unroll
    for (int nt=0;nt<2;nt++){
      int gcol = col0 + qc + nt*16 + l15;
      float b = bias ? bias[gcol] : 0.f;
      #pragma unroll
      for (int r=0;r<4;r++){
        int grow = row0 + qr + mt*16 + qrow + r;
        float val = acc[mt][nt][r] + b;
        if (flags & 1) val = silu_f(val);
        size_t o = (size_t)grow*Ncol + gcol;
        if (flags & 2) C[o] = val;
        if (flags & 16){
          u16 hb = f2bf(val);
          P1[o] = hb; P2[o] = f2bf(val - bf2f(hb));
        }
        if (flags & 4){
          u16 bb = f2bf(val);
          size_t rowo = (size_t)grow*F;
          if (gcol < F)        P1[(rowo + gcol)*2]       = bb;   // vv -> lo16
          else if (gcol < 2*F) P1[(rowo + gcol - F)*2+1] = bb;   // ss -> hi16
          else                 P1[2*(size_t)NF + rowo + gcol - 2*F] = bb; // vs
        }
      }
    }
}

// ------------------------------------------------- fused message aggregation
__global__ __launch_bounds__(256) void k_agg(const uint4* __restrict__ ed_g,
                                             const u16* __restrict__ phi_pk,
                                             const unsigned* __restrict__ rwp2,  // [11][3F]
                                             const u16* __restrict__ v_pk,
                                             const float* __restrict__ v_in,
                                             float* __restrict__ v_out,
                                             u16* __restrict__ vo_h,
                                             u16* __restrict__ vo_l,
                                             float* __restrict__ s,
                                             u16* __restrict__ s_h,
                                             u16* __restrict__ s_l){
  __shared__ uint4 ed4[2*DEG*4];    // 2 nodes x 16 edges x 64B
  int t = threadIdx.x;
  int half = t >> 7, f = t & 127;

  __half2 rw2[3][11];
  #pragma unroll
  for (int r2=0;r2<11;r2++){
    rw2[0][r2] = u2h2(rwp2[r2*F3 + f]);
    rw2[1][r2] = u2h2(rwp2[r2*F3 + F + f]);
    rw2[2][r2] = u2h2(rwp2[r2*F3 + 2*F + f]);
  }

  const unsigned* phiA = (const unsigned*)phi_pk;
  const u16*      phiB = phi_pk + 2*(size_t)NF;
  const unsigned* vpA  = (const unsigned*)v_pk;
  const u16*      vpB  = v_pk + 2*(size_t)NF;

  int n0 = blockIdx.x * AGG_G;
  for (int p=0;p<AGG_G/2;p++){
    int nA = n0 + 2*p;
    __syncthreads();
    if (t < 128) ed4[t] = ed_g[(size_t)nA*DEG*4 + t];
    __syncthreads();

    int n = nA + half;
    int base = half*DEG*4;
    float ds=0.f, dv0=0.f, dv1=0.f, dv2=0.f;

    int jn = (int)(ed4[base+3].z & (N_NODES-1));
    unsigned pa = phiA[(size_t)jn*F + f];
    u16      pb = phiB[(size_t)jn*F + f];
    unsigned va = vpA [(size_t)jn*F + f];
    u16      vb = vpB [(size_t)jn*F + f];
    for (int el=0;el<DEG;el++){
      unsigned cpa=pa; u16 cpb=pb; unsigned cva=va; u16 cvb=vb;
      if (el+1 < DEG){
        int j1 = (int)(ed4[base+(el+1)*4+3].z & (N_NODES-1));
        pa = phiA[(size_t)j1*F + f];
        pb = phiB[(size_t)j1*F + f];
        va = vpA [(size_t)j1*F + f];
        vb = vpB [(size_t)j1*F + f];
      }
      uint4 q0 = ed4[base+el*4+0];
      uint4 q1 = ed4[base+el*4+1];
      uint4 q2 = ed4[base+el*4+2];
      uint4 q3 = ed4[base+el*4+3];
      __half2 rc[11] = {u2h2(q0.x),u2h2(q0.y),u2h2(q0.z),u2h2(q0.w),
                        u2h2(q1.x),u2h2(q1.y),u2h2(q1.z),u2h2(q1.w),
                        u2h2(q2.x),u2h2(q2.y),u2h2(q2.z)};
      __half2 a0 = __hmul2(rc[0], rw2[0][0]);
      __half2 a1 = __hmul2(rc[0], rw2[1][0]);
      __half2 a2 = __hmul2(rc[0], rw2[2][0]);
      #pragma unroll
      for (int r2=1;r2<11;r2++){
        a0 = __hfma2(rc[r2], rw2[0][r2], a0);
        a1 = __hfma2(rc[r2], rw2[1][r2], a1);
        a2 = __hfma2(rc[r2], rw2[2][r2], a2);
      }
      float Wvv = __low2float(a0) + __high2float(a0);
      float Wss = __low2float(a1) + __high2float(a1);
      float Wvs = __low2float(a2) + __high2float(a2);
      float pvv = Wvv*lo_bf(cpa), pss = Wss*hi_bf(cpa), pvs = Wvs*bf2f(cpb);
      ds += pss;
      dv0 += lo_bf(cva)*pvv + pvs*__uint_as_float(q2.w);
      dv1 += hi_bf(cva)*pvv + pvs*__uint_as_float(q3.x);
      dv2 += bf2f(cvb)*pvv + pvs*__uint_as_float(q3.y);
    }
    size_t i = (size_t)n*F + f;
    const float inv = 1.f/DEG;
    float sv = s[i] + ds*inv;
    s[i] = sv;
    { u16 hb = f2bf(sv); s_h[i] = hb; s_l[i] = f2bf(sv - bf2f(hb)); }
    float o0 = v_in[i]      + dv0*inv;
    float o1 = v_in[NF+i]   + dv1*inv;
    float o2 = v_in[2*NF+i] + dv2*inv;
    v_out[i] = o0; v_out[NF+i] = o1; v_out[2*NF+i] = o2;
    u16 h0=f2bf(o0), h1=f2bf(o1), h2=f2bf(o2);
    vo_h[i]=h0; vo_h[NF+i]=h1; vo_h[2*NF+i]=h2;
    vo_l[i]=f2bf(o0-bf2f(h0)); vo_l[NF+i]=f2bf(o1-bf2f(h1)); vo_l[2*NF+i]=f2bf(o2-bf2f(h2));
  }
}

// ------------------------------------ fused Uv/Vv GEMM + dot/norm epilogue
__global__ __launch_bounds__(256) void k_uvdot(const u16* __restrict__ voh,
                                               const u16* __restrict__ vol,
                                               const u16* __restrict__ Bh_g,   // uvW [256][128]
                                               const u16* __restrict__ Bl_g,
                                               const float* __restrict__ s,
                                               float* __restrict__ uvF,        // [3][N][F]
                                               float* __restrict__ dot,
                                               u16* __restrict__ ai_h,
                                               u16* __restrict__ ai_l){
  __shared__ u16 Ah[64*40], Al[64*40], BUh[64*40], BUl[64*40], BVh[64*40], BVl[64*40]; // 30KB
  int t = threadIdx.x;
  int row0 = blockIdx.y<<6, c0 = blockIdx.x<<6;
  int sr = t>>2, sc = (t&3)<<3;
  int lane = t&63, w = t>>6;
  int qr = (w>>1)<<5, qc = (w&1)<<5;
  int l15 = lane&15, q8 = (lane>>4)<<3;
  int qrow = (lane>>4)<<2;
  f32x4 dA[2][2], nA[2][2];
  #pragma unroll
  for (int mt=0;mt<2;mt++)
    #pragma unroll
    for (int nt=0;nt<2;nt++){ dA[mt][nt][0]=0;dA[mt][nt][1]=0;dA[mt][nt][2]=0;dA[mt][nt][3]=0;
                              nA[mt][nt][0]=0;nA[mt][nt][1]=0;nA[mt][nt][2]=0;nA[mt][nt][3]=0; }

  for (int c=0;c<3;c++){
    f32x4 aU[2][2], aV[2][2];
    #pragma unroll
    for (int mt=0;mt<2;mt++)
      #pragma unroll
      for (int nt=0;nt<2;nt++){ aU[mt][nt][0]=0;aU[mt][nt][1]=0;aU[mt][nt][2]=0;aU[mt][nt][3]=0;
                                aV[mt][nt][0]=0;aV[mt][nt][1]=0;aV[mt][nt][2]=0;aV[mt][nt][3]=0; }
    const u16* Agh = voh + (size_t)c*NF + (size_t)(row0+sr)*F + sc;
    const u16* Agl = vol + (size_t)c*NF + (size_t)(row0+sr)*F + sc;
    const u16* BUgh = Bh_g + (size_t)(c0+sr)*F + sc;
    const u16* BUgl = Bl_g + (size_t)(c0+sr)*F + sc;
    const u16* BVgh = Bh_g + (size_t)(128+c0+sr)*F + sc;
    const u16* BVgl = Bl_g + (size_t)(128+c0+sr)*F + sc;
    for (int k0=0;k0<F;k0+=32){
      *(uint4*)&Ah[sr*40+sc]  = *(const uint4*)(Agh+k0);
      *(uint4*)&Al[sr*40+sc]  = *(const uint4*)(Agl+k0);
      *(uint4*)&BUh[sr*40+sc] = *(const uint4*)(BUgh+k0);
      *(uint4*)&BUl[sr*40+sc] = *(const uint4*)(BUgl+k0);
      *(uint4*)&BVh[sr*40+sc] = *(const uint4*)(BVgh+k0);
      *(uint4*)&BVl[sr*40+sc] = *(const uint4*)(BVgl+k0);
      __syncthreads();
      bf16x8 a_h[2], a_l[2], bu_h[2], bu_l[2], bv_h[2], bv_l[2];
      #pragma unroll
      for (int mt=0;mt<2;mt++){
        int off = (qr+mt*16+l15)*40 + q8;
        a_h[mt] = *(const bf16x8*)&Ah[off];
        a_l[mt] = *(const bf16x8*)&Al[off];
      }
      #pragma unroll
      for (int nt=0;nt<2;nt++){
        int off = (qc+nt*16+l15)*40 + q8;
        bu_h[nt] = *(const bf16x8*)&BUh[off];
        bu_l[nt] = *(const bf16x8*)&BUl[off];
        bv_h[nt] = *(const bf16x8*)&BVh[off];
        bv_l[nt] = *(const bf16x8*)&BVl[off];
      }
      #pragma unroll
      for (int mt=0;mt<2;mt++)
        #pragma unroll
        for (int nt=0;nt<2;nt++){
          aU[mt][nt] = __builtin_amdgcn_mfma_f32_16x16x32_bf16(a_h[mt], bu_h[nt], aU[mt][nt], 0,0,0);
          aU[mt][nt] = __builtin_amdgcn_mfma_f32_16x16x32_bf16(a_h[mt], bu_l[nt], aU[mt][nt], 0,0,0);
          aU[mt][nt] = __builtin_amdgcn_mfma_f32_16x16x32_bf16(a_l[mt], bu_h[nt], aU[mt][nt], 0,0,0);
          aV[mt][nt] = __builtin_amdgcn_mfma_f32_16x16x32_bf16(a_h[mt], bv_h[nt], aV[mt][nt], 0,0,0);
          aV[mt][nt] = __builtin_amdgcn_mfma_f32_16x16x32_bf16(a_h[mt], bv_l[nt], aV[mt][nt], 0,0,0);
          aV[mt][nt] = __builtin_amdgcn_mfma_f32_16x16x32_bf16(a_l[mt], bv_h[nt], aV[mt][nt], 0,0,0);
        }
      __syncthreads();
    }
    #pragma unroll
    for (int mt=0;mt<2;mt++)
      #pragma unroll
      for (int nt=0;nt<2;nt++){
        int gcol = c0 + qc + nt*16 + l15;
        #pragma unroll
        for (int r=0;r<4;r++){
          int grow = row0 + qr + mt*16 + qrow + r;
          float u = aU[mt][nt][r], v = aV[mt][nt][r];
          dA[mt][nt][r] += u*v;
          nA[mt][nt][r] += v*v;
          uvF[(size_t)c*NF + (size_t)grow*F + gcol] = u;
        }
      }
  }
  #pragma unroll
  for (int mt=0;mt<2;mt++)
    #pragma unroll
    for (int nt=0;nt<2;nt++){
      int gcol = c0 + qc + nt*16 + l15;
      #pragma unroll
      for (int r=0;r<4;r++){
        int grow = row0 + qr + mt*16 + qrow + r;
        dot[(size_t)grow*F + gcol] = dA[mt][nt][r];
        float vn = sqrtf(nA[mt][nt][r]);
        float sv = s[(size_t)grow*F + gcol];
        size_t b = (size_t)grow*256 + gcol;
        u16 h0 = f2bf(vn), h1 = f2bf(sv);
        ai_h[b] = h0;     ai_l[b] = f2bf(vn - bf2f(h0));
        ai_h[b+128] = h1; ai_l[b+128] = f2bf(sv - bf2f(h1));
      }
    }
}

// ------------------------------------------------------------- apply update
__global__ __launch_bounds__(256) void k_apply(const float* __restrict__ a,
                                               const float* __restrict__ dot,
                                               const float* __restrict__ uvF,
                                               float* __restrict__ s,
                                               u16* __restrict__ s_h,
                                               u16* __restrict__ s_l,
                                               float* __restrict__ v,
                                               u16* __restrict__ v_pk,
                                               float* __restrict__ out){
  int i = blockIdx.x*256 + threadIdx.x;
  int n = i >> 7, f = i & 127;
  const float* row = a + (size_t)n*F3;
  float avv = row[f], asv = row[F+f], ass = row[2*F+f];
  float sv = s[i] + ass + asv*dot[i];
  s[i] = sv;
  { u16 hb = f2bf(sv); s_h[i] = hb; s_l[i] = f2bf(sv - bf2f(hb)); }
  float nv0 = v[i]      + uvF[i]*avv;
  float nv1 = v[NF+i]   + uvF[NF+i]*avv;
  float nv2 = v[2*NF+i] + uvF[2*NF+i]*avv;
  v[i] = nv0; v[NF+i] = nv1; v[2*NF+i] = nv2;
  ((unsigned*)v_pk)[i] = (unsigned)f2bf(nv0) | ((unsigned)f2bf(nv1)<<16);
  v_pk[2*(size_t)NF + i] = f2bf(nv2);
  if (out){
    out[i] = sv;
    out[NF + (size_t)i*3 + 0] = nv0;
    out[NF + (size_t)i*3 + 1] = nv1;
    out[NF + (size_t)i*3 + 2] = nv2;
  }
}

// ------------------------------------------------------------------ launch
extern "C" void kernel_launch(void* const* d_in, const int* in_sizes, int n_in,
                              void* d_out, int out_size, void* d_ws, size_t ws_size,
                              hipStream_t stream) {
  const int* atoms   = (const int*)d_in[0];
  const int* idxj    = (const int*)d_in[2];

  float* W = (float*)d_ws;
  size_t off = 64;
  int* flag = (int*)d_ws;
  #define ALLOCF(name, cnt) float* name = W+off; off += (((cnt)+63)&~(size_t)63)
  #define ALLOCU(name, cnt) u16* name = (u16*)(W+off); off += ((((cnt)+1)/2+63)&~(size_t)63)
  ALLOCF(c_mb1, NLAYER*F);
  ALLOCF(c_mb2, NLAYER*F3);
  ALLOCF(c_b1,  NLAYER*F);
  ALLOCF(c_b2,  NLAYER*F3);
  unsigned* c_rwp2 = (unsigned*)(W+off); off += ((NLAYER*11*F3+63)&~(size_t)63);
  uint4* edata = (uint4*)(W+off); off += (size_t)NEDGE*16;  // E x 4 uint4 = E*64B = E*16 floats
  ALLOCU(w_mw1h, NLAYER*F*F);   ALLOCU(w_mw1l, NLAYER*F*F);
  ALLOCU(w_mw2h, NLAYER*F*F3);  ALLOCU(w_mw2l, NLAYER*F*F3);
  ALLOCU(w_uvh,  NLAYER*256*F); ALLOCU(w_uvl,  NLAYER*256*F);
  ALLOCU(w_w1h,  NLAYER*F*256); ALLOCU(w_w1l,  NLAYER*F*256);
  ALLOCU(w_w2h,  NLAYER*F*F3);  ALLOCU(w_w2l,  NLAYER*F*F3);
  ALLOCU(phi_pk, (size_t)3*NF);
  ALLOCU(v_pk,   (size_t)3*NF);
  ALLOCU(s_h,  NF); ALLOCU(s_l,  NF);
  ALLOCU(h_h,  NF); ALLOCU(h_l,  NF);
  ALLOCU(ai_h, (size_t)2*NF); ALLOCU(ai_l, (size_t)2*NF);
  ALLOCU(vo_h, (size_t)3*NF); ALLOCU(vo_l, (size_t)3*NF);
  ALLOCF(s,    NF);
  ALLOCF(vA,   (size_t)3*NF);
  ALLOCF(vB,   (size_t)3*NF);
  ALLOCF(uvF,  (size_t)3*NF);
  ALLOCF(dotb, NF);

  k_detect<<<1, 64, 0, stream>>>((const u16*)d_in[4], flag);
  k_prep<<<(PREP_TOTAL+255)/256, 256, 0, stream>>>(
      d_in[7], d_in[9], d_in[15], d_in[17],
      d_in[10], d_in[11],
      d_in[6], d_in[8], d_in[14], d_in[16],
      d_in[12], d_in[13],
      d_in[4], d_in[3], idxj,
      c_mb1, c_mb2, c_b1, c_b2, c_rwp2,
      w_mw1h, w_mw1l, w_mw2h, w_mw2l, w_w1h, w_w1l,
      w_w2h, w_w2l, w_uvh, w_uvl, edata, flag);

  k_init<<<NF/256, 256, 0, stream>>>(atoms, d_in[5], s, s_h, s_l, vA, v_pk, flag);

  for (int l=0; l<NLAYER; l++){
    float* vin  = (l & 1) ? vB : vA;
    float* vout = (l & 1) ? vA : vB;
    // ---- message block ----
    k_mgemm<<<dim3(F/64, N_NODES/64), 256, 0, stream>>>(
        s_h, s_l, w_mw1h + (size_t)l*F*F, w_mw1l + (size_t)l*F*F,
        c_mb1 + (size_t)l*F, nullptr, h_h, h_l, N_NODES, F, F, 1|16);
    k_mgemm<<<dim3(F3/64, N_NODES/64), 256, 0, stream>>>(
        h_h, h_l, w_mw2h + (size_t)l*F*F3, w_mw2l + (size_t)l*F*F3,
        c_mb2 + (size_t)l*F3, nullptr, phi_pk, nullptr, N_NODES, F3, F, 4);
    k_agg<<<N_NODES/AGG_G, 256, 0, stream>>>(
        edata, phi_pk, c_rwp2 + (size_t)l*11*F3,
        v_pk, vin, vout, vo_h, vo_l, s, s_h, s_l);
    // ---- update block ----
    k_uvdot<<<dim3(2, N_NODES/64), 256, 0, stream>>>(
        vo_h, vo_l, w_uvh + (size_t)l*256*F, w_uvl + (size_t)l*256*F,
        s, uvF, dotb, ai_h, ai_l);
    k_mgemm<<<dim3(F/64, N_NODES/64), 256, 0, stream>>>(
        ai_h, ai_l, w_w1h + (size_t)l*F*256, w_w1l + (size_t)l*F*256,
        c_b1 + (size_t)l*F, nullptr, h_h, h_l, N_NODES, F, 2*F, 1|16);
    k_mgemm<<<dim3(F3/64, N_NODES/64), 256, 0, stream>>>(
        h_h, h_l, w_w2h + (size_t)l*F*F3, w_w2l + (size_t)l*F*F3,
        c_b2 + (size_t)l*F3, vin, nullptr, nullptr, N_NODES, F3, F, 2);
    k_apply<<<NF/256, 256, 0, stream>>>(vin, dotb, uvF, s, s_h, s_l, vout, v_pk,
                                        (l == NLAYER-1) ? (float*)d_out : nullptr);
  }
}

// Round 10
// 426.003 us; speedup vs baseline: 1.2506x; 1.0463x over previous
//
#include <hip/hip_runtime.h>
#include <hip/hip_fp16.h>

#define N_NODES 8192
#define DEG     16
#define NEDGE   (N_NODES*DEG)
#define F       128
#define F3      384
#define RBF     20
#define NLAYER  3
#define NF      (N_NODES*F)
#define PI_F    3.14159265358979f

typedef unsigned short u16;
typedef __bf16 bf16x8 __attribute__((ext_vector_type(8)));
typedef float  f32x4  __attribute__((ext_vector_type(4)));

__device__ __forceinline__ float bf2f(u16 u){ return __uint_as_float(((unsigned)u)<<16); }
__device__ __forceinline__ u16 f2bf(float f){
  unsigned x = __float_as_uint(f);
  unsigned r = (x + 0x7FFFu + ((x>>16)&1u)) >> 16;   // RNE
  return (u16)r;
}
__device__ __forceinline__ float lo_bf(unsigned u){ return __uint_as_float(u<<16); }
__device__ __forceinline__ float hi_bf(unsigned u){ return __uint_as_float(u & 0xFFFF0000u); }
__device__ __forceinline__ float silu_f(float x){ return x / (1.f + __expf(-x)); }
__device__ __forceinline__ float ldsrc(const void* src, int i, int bf){
  return bf ? bf2f(((const u16*)src)[i]) : ((const float*)src)[i];
}
__device__ __forceinline__ unsigned packh2(float a, float b){
  return (unsigned)__half_as_ushort(__float2half(a)) |
         ((unsigned)__half_as_ushort(__float2half(b)) << 16);
}
__device__ __forceinline__ __half2 u2h2(unsigned u){ return __builtin_bit_cast(__half2, u); }

// ------------------------------------------------------------ dtype detect
__global__ void k_detect(const u16* __restrict__ rd, int* __restrict__ flag){
  if (threadIdx.x == 0 && blockIdx.x == 0){
    int ok = 1;
    for (int i = 0; i < 128; i++){
      float v = bf2f(rd[2*i]);
      if (!(v > 0.01f && v < 4.0f)) { ok = 0; break; }
    }
    *flag = ok;   // 1 = inputs bf16, 0 = fp32
  }
}

// ------------------------------------------- split helper: [L][K][N] -> [L][N][K] hi/lo
__device__ __forceinline__ void splitw(const void* src, u16* bh, u16* bl,
                                       int i, int K, int Ncol, int bf){
  int kn = K*Ncol; int l = i/kn; int r = i - l*kn; int k = r/Ncol; int n = r - k*Ncol;
  float w = ldsrc(src, i, bf);
  u16 h = f2bf(w);
  size_t o = (size_t)l*kn + (size_t)n*K + k;
  bh[o] = h; bl[o] = f2bf(w - bf2f(h));
}

// -------------------------------------- fused preamble (weights + edges + node init)
__global__ __launch_bounds__(256) void k_prep(
    const void* mb1, const void* mb2, const void* b1, const void* b2,
    const void* rw,  const void* rb,
    const void* mw1, const void* mw2, const void* w1, const void* w2,
    const void* Uw,  const void* Vw,
    const void* dist, const void* dirv, const int* __restrict__ idxj,
    const int* __restrict__ atoms, const void* __restrict__ emb,
    float* c_mb1, float* c_mb2, float* c_b1, float* c_b2,
    unsigned* rwp2,                 // [L][11][3F]
    u16* mw1h, u16* mw1l, u16* mw2h, u16* mw2l, u16* w1h, u16* w1l,
    u16* w2h, u16* w2l, u16* uvh, u16* uvl,
    uint4* edata,                   // [E][4]
    float* s, u16* s_h, u16* s_l,
    u16* p0h, u16* p0l, u16* bufA16, u16* bufB16,
    const int* __restrict__ flag){
  int i = blockIdx.x*256 + threadIdx.x;
  int bf = *flag;
  const int S0=NLAYER*F, S1=NLAYER*F3, S2=NLAYER*F, S3=NLAYER*F3;
  const int S4=NLAYER*11*F3;
  const int S5=NLAYER*F*F, S6=NLAYER*F*F3, S7=NLAYER*2*F*F, S8=NLAYER*F*F3, S9=NLAYER*256*F;
  if (i < S0){ c_mb1[i]=ldsrc(mb1,i,bf); return; } i-=S0;
  if (i < S1){ c_mb2[i]=ldsrc(mb2,i,bf); return; } i-=S1;
  if (i < S2){ c_b1[i] =ldsrc(b1, i,bf); return; } i-=S2;
  if (i < S3){ c_b2[i] =ldsrc(b2, i,bf); return; } i-=S3;
  if (i < S4){
    int l = i/(11*F3); int r = i - l*(11*F3); int r2 = r/F3; int col = r - r2*F3;
    float w0, w1v;
    if (r2 < 10){
      w0  = ldsrc(rw, (l*RBF + 2*r2  )*F3 + col, bf);
      w1v = ldsrc(rw, (l*RBF + 2*r2+1)*F3 + col, bf);
    } else {
      w0  = ldsrc(rb, l*F3 + col, bf);
      w1v = 0.f;
    }
    rwp2[i] = packh2(w0, w1v);
    return;
  } i-=S4;
  if (i < S5){ splitw(mw1, mw1h, mw1l, i, F,   F,  bf); return; } i-=S5;
  if (i < S6){ splitw(mw2, mw2h, mw2l, i, F,   F3, bf); return; } i-=S6;
  if (i < S7){ splitw(w1,  w1h,  w1l,  i, 2*F, F,  bf); return; } i-=S7;
  if (i < S8){ splitw(w2,  w2h,  w2l,  i, F,   F3, bf); return; } i-=S8;
  if (i < S9){
    int l=i/(256*F); int r=i-l*(256*F); int n=r>>7; int k=r&127;
    int si=(l*F+k)*F+(n&127);
    float w = ldsrc((n<128)?Uw:Vw, si, bf);
    u16 h=f2bf(w); uvh[i]=h; uvl[i]=f2bf(w-bf2f(h));
    return;
  } i-=S9;
  if (i < NEDGE){
    int e = i;
    float d = ldsrc(dist, e, bf);
    float cut = 0.5f*(cosf(PI_F*d*(1.f/3.f)) + 1.0f);
    float ic = cut/d;
    unsigned o[16];
    #pragma unroll
    for (int r2=0;r2<10;r2++){
      float s0 = sinf((2*r2+1)*PI_F*d*(1.f/3.f))*ic;
      float s1 = sinf((2*r2+2)*PI_F*d*(1.f/3.f))*ic;
      o[r2] = packh2(s0, s1);
    }
    o[10] = packh2(cut, 0.f);
    o[11] = __float_as_uint(ldsrc(dirv, e*3+0, bf));
    o[12] = __float_as_uint(ldsrc(dirv, e*3+1, bf));
    o[13] = __float_as_uint(ldsrc(dirv, e*3+2, bf));
    o[14] = (unsigned)idxj[e];
    o[15] = 0;
    uint4* dst = edata + (size_t)e*4;
    dst[0] = make_uint4(o[0],o[1],o[2],o[3]);
    dst[1] = make_uint4(o[4],o[5],o[6],o[7]);
    dst[2] = make_uint4(o[8],o[9],o[10],o[11]);
    dst[3] = make_uint4(o[12],o[13],o[14],o[15]);
    return;
  } i-=NEDGE;
  if (i < NF){                      // node init
    int n = i >> 7, f = i & 127;
    float sv = ldsrc(emb, atoms[n]*F + f, bf);
    s[i] = sv;
    u16 hb = f2bf(sv); s_h[i] = hb; s_l[i] = f2bf(sv - bf2f(hb));
    p0h[i]=0; p0h[NF+i]=0; p0h[2*(size_t)NF+i]=0;
    p0l[i]=0; p0l[NF+i]=0; p0l[2*(size_t)NF+i]=0;
    bufA16[(size_t)i*4+2]=0; bufA16[(size_t)i*4+3]=0;
    bufB16[(size_t)i*2+1]=0;
  }
}
#define PREP_TOTAL (NLAYER*(F+F3+F+F3+11*F3+F*F+F*F3+2*F*F+F*F3+256*F) + NEDGE + NF)

// ------------------------------------------------ split-bf16 MFMA GEMM, 32x64 tile
// flags: 1=silu, 2=write f32 C, 4=write packed phi halfwords to P1/P2, 16=split planes P1/P2.
__global__ __launch_bounds__(256) void k_mgemm(const u16* __restrict__ Ah_g,
                                               const u16* __restrict__ Al_g,
                                               const u16* __restrict__ Bh_g,
                                               const u16* __restrict__ Bl_g,
                                               const float* __restrict__ bias,
                                               float* __restrict__ C,
                                               u16* __restrict__ P1,
                                               u16* __restrict__ P2,
                                               int M, int Ncol, int K, int flags){
  __shared__ u16 Ah[32*40], Al[32*40], Bh[64*40], Bl[64*40];   // 15 KB
  int t = threadIdx.x;
  int row0 = blockIdx.y<<5, col0 = blockIdx.x<<6;
  int lane = t&63, w = t>>6;
  int qr = (w>>1)<<4, qc = (w&1)<<5;
  int l15 = lane&15, q8 = (lane>>4)<<3;
  int ap = t>>7, arem = t&127, ar = arem>>2, ac = (arem&3)<<3;
  const u16* Asrc = (ap ? Al_g : Ah_g) + (size_t)(row0+ar)*K + ac;
  u16* Adst = (ap ? Al : Ah) + ar*40 + ac;
  f32x4 acc[2];
  acc[0][0]=0;acc[0][1]=0;acc[0][2]=0;acc[0][3]=0;
  acc[1][0]=0;acc[1][1]=0;acc[1][2]=0;acc[1][3]=0;

  for (int k0=0;k0<K;k0+=32){
    *(uint4*)Adst = *(const uint4*)(Asrc + k0);
    #pragma unroll
    for (int q=0;q<2;q++){
      int idx = t + 256*q;
      int bp = idx>>8, rem = idx&255, br = rem>>2, bc = (rem&3)<<3;
      const u16* Bsrc = (bp ? Bl_g : Bh_g) + (size_t)(col0+br)*K + k0 + bc;
      *(uint4*)((bp ? Bl : Bh) + br*40 + bc) = *(const uint4*)Bsrc;
    }
    __syncthreads();
    bf16x8 a_h = *(const bf16x8*)&Ah[(qr+l15)*40 + q8];
    bf16x8 a_l = *(const bf16x8*)&Al[(qr+l15)*40 + q8];
    #pragma unroll
    for (int nt=0;nt<2;nt++){
      int off = (qc+nt*16+l15)*40 + q8;
      bf16x8 b_h = *(const bf16x8*)&Bh[off];
      bf16x8 b_l = *(const bf16x8*)&Bl[off];
      acc[nt] = __builtin_amdgcn_mfma_f32_16x16x32_bf16(a_h, b_h, acc[nt], 0,0,0);
      acc[nt] = __builtin_amdgcn_mfma_f32_16x16x32_bf16(a_h, b_l, acc[nt], 0,0,0);
      acc[nt] = __builtin_amdgcn_mfma_f32_16x16x32_bf16(a_l, b_h, acc[nt], 0,0,0);
    }
    __syncthreads();
  }

  int qrow = (lane>>4)<<2;
  #pragma unroll
  for (int nt=0;nt<2;nt++){
    int gcol = col0 + qc + nt*16 + l15;
    float b = bias ? bias[gcol] : 0.f;
    #pragma unroll
    for (int r=0;r<4;r++){
      int grow = row0 + qr + qrow + r;
      float val = acc[nt][r] + b;
      if (flags & 1) val = silu_f(val);
      size_t o = (size_t)grow*Ncol + gcol;
      if (flags & 2) C[o] = val;
      if (flags & 16){
        u16 hb = f2bf(val);
        P1[o] = hb; P2[o] = f2bf(val - bf2f(hb));
      }
      if (flags & 4){
        u16 bb = f2bf(val);
        size_t rowo = (size_t)grow*F;
        if (gcol < F)        P1[(rowo + gcol)*4 + 0]     = bb;  // phi_vv
        else if (gcol < 2*F) P1[(rowo + gcol - F)*4 + 1] = bb;  // phi_ss
        else                 P2[(rowo + gcol - 2*F)*2]   = bb;  // phi_vs
      }
    }
  }
}

// ------------------------------------------------- fused message aggregation
// 2 nodes per block (grid 4096); 2 gathers/edge (uint2 + u32).
__global__ __launch_bounds__(256) void k_agg(const uint4* __restrict__ ed_g,
                                             const uint2* __restrict__ bufA,
                                             const unsigned* __restrict__ bufB,
                                             const unsigned* __restrict__ rwp2,  // [11][3F]
                                             const u16* __restrict__ vi_h,
                                             const u16* __restrict__ vi_l,
                                             u16* __restrict__ vo_h,
                                             u16* __restrict__ vo_l,
                                             float* __restrict__ s,
                                             u16* __restrict__ s_h,
                                             u16* __restrict__ s_l){
  __shared__ uint4 ed4[128];        // 2 nodes x 16 edges x 64B
  int t = threadIdx.x;
  int half = t >> 7, f = t & 127;

  __half2 rw2[3][11];
  #pragma unroll
  for (int r2=0;r2<11;r2++){
    rw2[0][r2] = u2h2(rwp2[r2*F3 + f]);
    rw2[1][r2] = u2h2(rwp2[r2*F3 + F + f]);
    rw2[2][r2] = u2h2(rwp2[r2*F3 + 2*F + f]);
  }

  int nA = blockIdx.x * 2;
  if (t < 128) ed4[t] = ed_g[(size_t)nA*64 + t];
  __syncthreads();

  int n = nA + half;
  int base = half*64;
  float ds=0.f, dv0=0.f, dv1=0.f, dv2=0.f;

  int j0 = (int)(ed4[base+3].z & (N_NODES-1));
  uint2    pa = bufA[(size_t)j0*F + f];
  unsigned pb = bufB[(size_t)j0*F + f];
  for (int el=0;el<DEG;el++){
    uint2 cpa = pa; unsigned cpb = pb;
    if (el+1 < DEG){
      int j1 = (int)(ed4[base+(el+1)*4+3].z & (N_NODES-1));
      pa = bufA[(size_t)j1*F + f];
      pb = bufB[(size_t)j1*F + f];
    }
    uint4 q0 = ed4[base+el*4+0];
    uint4 q1 = ed4[base+el*4+1];
    uint4 q2 = ed4[base+el*4+2];
    uint4 q3 = ed4[base+el*4+3];
    __half2 rc[11] = {u2h2(q0.x),u2h2(q0.y),u2h2(q0.z),u2h2(q0.w),
                      u2h2(q1.x),u2h2(q1.y),u2h2(q1.z),u2h2(q1.w),
                      u2h2(q2.x),u2h2(q2.y),u2h2(q2.z)};
    __half2 a0 = __hmul2(rc[0], rw2[0][0]);
    __half2 a1 = __hmul2(rc[0], rw2[1][0]);
    __half2 a2 = __hmul2(rc[0], rw2[2][0]);
    #pragma unroll
    for (int r2=1;r2<11;r2++){
      a0 = __hfma2(rc[r2], rw2[0][r2], a0);
      a1 = __hfma2(rc[r2], rw2[1][r2], a1);
      a2 = __hfma2(rc[r2], rw2[2][r2], a2);
    }
    float Wvv = __low2float(a0) + __high2float(a0);
    float Wss = __low2float(a1) + __high2float(a1);
    float Wvs = __low2float(a2) + __high2float(a2);
    float pvv = Wvv*lo_bf(cpa.x), pss = Wss*hi_bf(cpa.x), pvs = Wvs*lo_bf(cpb);
    ds += pss;
    dv0 += lo_bf(cpa.y)*pvv + pvs*__uint_as_float(q2.w);
    dv1 += hi_bf(cpa.y)*pvv + pvs*__uint_as_float(q3.x);
    dv2 += hi_bf(cpb)  *pvv + pvs*__uint_as_float(q3.y);
  }
  size_t i = (size_t)n*F + f;
  const float inv = 1.f/DEG;
  float sv = s[i] + ds*inv;
  s[i] = sv;
  { u16 hb = f2bf(sv); s_h[i] = hb; s_l[i] = f2bf(sv - bf2f(hb)); }
  float o0 = bf2f(vi_h[i])            + bf2f(vi_l[i])            + dv0*inv;
  float o1 = bf2f(vi_h[NF+i])         + bf2f(vi_l[NF+i])         + dv1*inv;
  float o2 = bf2f(vi_h[2*(size_t)NF+i]) + bf2f(vi_l[2*(size_t)NF+i]) + dv2*inv;
  u16 h0=f2bf(o0), h1=f2bf(o1), h2=f2bf(o2);
  vo_h[i]=h0; vo_h[NF+i]=h1; vo_h[2*(size_t)NF+i]=h2;
  vo_l[i]=f2bf(o0-bf2f(h0)); vo_l[NF+i]=f2bf(o1-bf2f(h1)); vo_l[2*(size_t)NF+i]=f2bf(o2-bf2f(h2));
}

// ------------------------------------ fused Uv/Vv GEMM + dot/norm, 32x64 tile
__global__ __launch_bounds__(256) void k_uvdot(const u16* __restrict__ voh,
                                               const u16* __restrict__ vol,
                                               const u16* __restrict__ Bh_g,   // uvW [256][128]
                                               const u16* __restrict__ Bl_g,
                                               const float* __restrict__ s,
                                               float* __restrict__ uvF,        // [3][N][F]
                                               float* __restrict__ dot,
                                               u16* __restrict__ ai_h,
                                               u16* __restrict__ ai_l){
  __shared__ u16 Ah[32*40], Al[32*40], BUh[64*40], BUl[64*40], BVh[64*40], BVl[64*40]; // 25.6KB
  int t = threadIdx.x;
  int row0 = blockIdx.y<<5, c0 = blockIdx.x<<6;
  int lane = t&63, w = t>>6;
  int qr = (w>>1)<<4, qc = (w&1)<<5;
  int l15 = lane&15, q8 = (lane>>4)<<3;
  int qrow = (lane>>4)<<2;
  int ap = t>>7, arem = t&127, ar = arem>>2, ac = (arem&3)<<3;
  f32x4 dA[2], nA2[2];
  dA[0][0]=0;dA[0][1]=0;dA[0][2]=0;dA[0][3]=0; dA[1]=dA[0];
  nA2[0]=dA[0]; nA2[1]=dA[0];

  for (int c=0;c<3;c++){
    f32x4 aU[2], aV[2];
    aU[0][0]=0;aU[0][1]=0;aU[0][2]=0;aU[0][3]=0; aU[1]=aU[0];
    aV[0]=aU[0]; aV[1]=aU[0];
    const u16* Asrc = (ap ? vol : voh) + (size_t)c*NF + (size_t)(row0+ar)*F + ac;
    u16* Adst = (ap ? Al : Ah) + ar*40 + ac;
    for (int k0=0;k0<F;k0+=32){
      *(uint4*)Adst = *(const uint4*)(Asrc + k0);
      #pragma unroll
      for (int q=0;q<4;q++){
        int idx = t + 256*q;
        int bp = idx>>8, rem = idx&255, br = rem>>2, bc = (rem&3)<<3;
        int grow = ((bp>>1) ? 128 : 0) + c0 + br;            // U rows then V rows
        const u16* Bsrc = ((bp&1) ? Bl_g : Bh_g) + (size_t)grow*F + k0 + bc;
        u16* Bdst;
        if (bp==0) Bdst = BUh; else if (bp==1) Bdst = BUl; else if (bp==2) Bdst = BVh; else Bdst = BVl;
        *(uint4*)(Bdst + br*40 + bc) = *(const uint4*)Bsrc;
      }
      __syncthreads();
      bf16x8 a_h = *(const bf16x8*)&Ah[(qr+l15)*40 + q8];
      bf16x8 a_l = *(const bf16x8*)&Al[(qr+l15)*40 + q8];
      #pragma unroll
      for (int nt=0;nt<2;nt++){
        int off = (qc+nt*16+l15)*40 + q8;
        bf16x8 bu_h = *(const bf16x8*)&BUh[off];
        bf16x8 bu_l = *(const bf16x8*)&BUl[off];
        bf16x8 bv_h = *(const bf16x8*)&BVh[off];
        bf16x8 bv_l = *(const bf16x8*)&BVl[off];
        aU[nt] = __builtin_amdgcn_mfma_f32_16x16x32_bf16(a_h, bu_h, aU[nt], 0,0,0);
        aU[nt] = __builtin_amdgcn_mfma_f32_16x16x32_bf16(a_h, bu_l, aU[nt], 0,0,0);
        aU[nt] = __builtin_amdgcn_mfma_f32_16x16x32_bf16(a_l, bu_h, aU[nt], 0,0,0);
        aV[nt] = __builtin_amdgcn_mfma_f32_16x16x32_bf16(a_h, bv_h, aV[nt], 0,0,0);
        aV[nt] = __builtin_amdgcn_mfma_f32_16x16x32_bf16(a_h, bv_l, aV[nt], 0,0,0);
        aV[nt] = __builtin_amdgcn_mfma_f32_16x16x32_bf16(a_l, bv_h, aV[nt], 0,0,0);
      }
      __syncthreads();
    }
    #pragma unroll
    for (int nt=0;nt<2;nt++){
      int gcol = c0 + qc + nt*16 + l15;
      #pragma unroll
      for (int r=0;r<4;r++){
        int grow = row0 + qr + qrow + r;
        float u = aU[nt][r], v = aV[nt][r];
        dA[nt][r] += u*v;
        nA2[nt][r] += v*v;
        uvF[(size_t)c*NF + (size_t)grow*F + gcol] = u;
      }
    }
  }
  #pragma unroll
  for (int nt=0;nt<2;nt++){
    int gcol = c0 + qc + nt*16 + l15;
    #pragma unroll
    for (int r=0;r<4;r++){
      int grow = row0 + qr + qrow + r;
      dot[(size_t)grow*F + gcol] = dA[nt][r];
      float vn = sqrtf(nA2[nt][r]);
      float sv = s[(size_t)grow*F + gcol];
      size_t b = (size_t)grow*256 + gcol;
      u16 h0 = f2bf(vn), h1 = f2bf(sv);
      ai_h[b] = h0;     ai_l[b] = f2bf(vn - bf2f(h0));
      ai_h[b+128] = h1; ai_l[b+128] = f2bf(sv - bf2f(h1));
    }
  }
}

// ------------------------------------------------------------- apply update
__global__ __launch_bounds__(256) void k_apply(const float* __restrict__ aF,
                                               const float* __restrict__ dot,
                                               const float* __restrict__ uvF,
                                               float* __restrict__ s,
                                               u16* __restrict__ s_h,
                                               u16* __restrict__ s_l,
                                               u16* __restrict__ v_h,     // in-place planes
                                               u16* __restrict__ v_l,
                                               u16* __restrict__ bufA16,
                                               u16* __restrict__ bufB16,
                                               float* __restrict__ out){
  int i = blockIdx.x*256 + threadIdx.x;
  int n = i >> 7, f = i & 127;
  const float* row = aF + (size_t)n*F3;
  float avv = row[f], asv = row[F+f], ass = row[2*F+f];
  float sv = s[i] + ass + asv*dot[i];
  s[i] = sv;
  { u16 hb = f2bf(sv); s_h[i] = hb; s_l[i] = f2bf(sv - bf2f(hb)); }
  float nv0 = bf2f(v_h[i])              + bf2f(v_l[i])              + uvF[i]*avv;
  float nv1 = bf2f(v_h[NF+i])           + bf2f(v_l[NF+i])           + uvF[NF+i]*avv;
  float nv2 = bf2f(v_h[2*(size_t)NF+i]) + bf2f(v_l[2*(size_t)NF+i]) + uvF[2*(size_t)NF+i]*avv;
  u16 h0=f2bf(nv0), h1=f2bf(nv1), h2=f2bf(nv2);
  v_h[i]=h0; v_h[NF+i]=h1; v_h[2*(size_t)NF+i]=h2;
  v_l[i]=f2bf(nv0-bf2f(h0)); v_l[NF+i]=f2bf(nv1-bf2f(h1)); v_l[2*(size_t)NF+i]=f2bf(nv2-bf2f(h2));
  bufA16[(size_t)i*4+2] = h0; bufA16[(size_t)i*4+3] = h1;
  bufB16[(size_t)i*2+1] = h2;
  if (out){
    out[i] = sv;
    out[NF + (size_t)i*3 + 0] = nv0;
    out[NF + (size_t)i*3 + 1] = nv1;
    out[NF + (size_t)i*3 + 2] = nv2;
  }
}

// ------------------------------------------------------------------ launch
extern "C" void kernel_launch(void* const* d_in, const int* in_sizes, int n_in,
                              void* d_out, int out_size, void* d_ws, size_t ws_size,
                              hipStream_t stream) {
  const int* atoms   = (const int*)d_in[0];
  const int* idxj    = (const int*)d_in[2];

  float* W = (float*)d_ws;
  size_t off = 64;
  int* flag = (int*)d_ws;
  #define ALLOCF(name, cnt) float* name = W+off; off += (((cnt)+63)&~(size_t)63)
  #define ALLOCU(name, cnt) u16* name = (u16*)(W+off); off += ((((cnt)+1)/2+63)&~(size_t)63)
  ALLOCF(c_mb1, NLAYER*F);
  ALLOCF(c_mb2, NLAYER*F3);
  ALLOCF(c_b1,  NLAYER*F);
  ALLOCF(c_b2,  NLAYER*F3);
  unsigned* c_rwp2 = (unsigned*)(W+off); off += ((NLAYER*11*F3+63)&~(size_t)63);
  uint4* edata = (uint4*)(W+off); off += (size_t)NEDGE*16;  // E x 64B = E*16 floats
  ALLOCU(w_mw1h, NLAYER*F*F);   ALLOCU(w_mw1l, NLAYER*F*F);
  ALLOCU(w_mw2h, NLAYER*F*F3);  ALLOCU(w_mw2l, NLAYER*F*F3);
  ALLOCU(w_uvh,  NLAYER*256*F); ALLOCU(w_uvl,  NLAYER*256*F);
  ALLOCU(w_w1h,  NLAYER*F*256); ALLOCU(w_w1l,  NLAYER*F*256);
  ALLOCU(w_w2h,  NLAYER*F*F3);  ALLOCU(w_w2l,  NLAYER*F*F3);
  uint2* bufA = (uint2*)(W+off); off += (size_t)2*NF;       // NF x 8B
  unsigned* bufB = (unsigned*)(W+off); off += (size_t)NF;   // NF x 4B
  ALLOCU(p0h, (size_t)3*NF); ALLOCU(p0l, (size_t)3*NF);
  ALLOCU(p1h, (size_t)3*NF); ALLOCU(p1l, (size_t)3*NF);
  ALLOCU(s_h,  NF); ALLOCU(s_l,  NF);
  ALLOCU(h_h,  NF); ALLOCU(h_l,  NF);
  ALLOCU(ai_h, (size_t)2*NF); ALLOCU(ai_l, (size_t)2*NF);
  ALLOCF(s,    NF);
  ALLOCF(uvF,  (size_t)3*NF);
  ALLOCF(dotb, NF);
  ALLOCF(aF,   (size_t)3*NF);

  k_detect<<<1, 64, 0, stream>>>((const u16*)d_in[4], flag);
  k_prep<<<(PREP_TOTAL+255)/256, 256, 0, stream>>>(
      d_in[7], d_in[9], d_in[15], d_in[17],
      d_in[10], d_in[11],
      d_in[6], d_in[8], d_in[14], d_in[16],
      d_in[12], d_in[13],
      d_in[4], d_in[3], idxj,
      atoms, d_in[5],
      c_mb1, c_mb2, c_b1, c_b2, c_rwp2,
      w_mw1h, w_mw1l, w_mw2h, w_mw2l, w_w1h, w_w1l,
      w_w2h, w_w2l, w_uvh, w_uvl, edata,
      s, s_h, s_l, p0h, p0l, (u16*)bufA, (u16*)bufB, flag);

  for (int l=0; l<NLAYER; l++){
    u16* vih = (l & 1) ? p1h : p0h;
    u16* vil = (l & 1) ? p1l : p0l;
    u16* voh = (l & 1) ? p0h : p1h;
    u16* vol = (l & 1) ? p0l : p1l;
    // ---- message block ----
    k_mgemm<<<dim3(F/64, N_NODES/32), 256, 0, stream>>>(
        s_h, s_l, w_mw1h + (size_t)l*F*F, w_mw1l + (size_t)l*F*F,
        c_mb1 + (size_t)l*F, nullptr, h_h, h_l, N_NODES, F, F, 1|16);
    k_mgemm<<<dim3(F3/64, N_NODES/32), 256, 0, stream>>>(
        h_h, h_l, w_mw2h + (size_t)l*F*F3, w_mw2l + (size_t)l*F*F3,
        c_mb2 + (size_t)l*F3, nullptr, (u16*)bufA, (u16*)bufB, N_NODES, F3, F, 4);
    k_agg<<<N_NODES/2, 256, 0, stream>>>(
        edata, bufA, bufB, c_rwp2 + (size_t)l*11*F3,
        vih, vil, voh, vol, s, s_h, s_l);
    // ---- update block ----
    k_uvdot<<<dim3(2, N_NODES/32), 256, 0, stream>>>(
        voh, vol, w_uvh + (size_t)l*256*F, w_uvl + (size_t)l*256*F,
        s, uvF, dotb, ai_h, ai_l);
    k_mgemm<<<dim3(F/64, N_NODES/32), 256, 0, stream>>>(
        ai_h, ai_l, w_w1h + (size_t)l*F*256, w_w1l + (size_t)l*F*256,
        c_b1 + (size_t)l*F, nullptr, h_h, h_l, N_NODES, F, 2*F, 1|16);
    k_mgemm<<<dim3(F3/64, N_NODES/32), 256, 0, stream>>>(
        h_h, h_l, w_w2h + (size_t)l*F*F3, w_w2l + (size_t)l*F*F3,
        c_b2 + (size_t)l*F3, aF, nullptr, nullptr, N_NODES, F3, F, 2);
    k_apply<<<NF/256, 256, 0, stream>>>(aF, dotb, uvF, s, s_h, s_l, voh, vol,
                                        (u16*)bufA, (u16*)bufB,
                                        (l == NLAYER-1) ? (float*)d_out : nullptr);
  }
}

// Round 11
// 388.510 us; speedup vs baseline: 1.3713x; 1.0965x over previous
//
#include <hip/hip_runtime.h>
#include <hip/hip_fp16.h>

#define N_NODES 8192
#define DEG     16
#define NEDGE   (N_NODES*DEG)
#define F       128
#define F3      384
#define RBF     20
#define NLAYER  3
#define NF      (N_NODES*F)
#define PI_F    3.14159265358979f

typedef unsigned short u16;
typedef __bf16 bf16x8 __attribute__((ext_vector_type(8)));
typedef float  f32x4  __attribute__((ext_vector_type(4)));

__device__ __forceinline__ float bf2f(u16 u){ return __uint_as_float(((unsigned)u)<<16); }
__device__ __forceinline__ u16 f2bf(float f){
  unsigned x = __float_as_uint(f);
  unsigned r = (x + 0x7FFFu + ((x>>16)&1u)) >> 16;   // RNE
  return (u16)r;
}
__device__ __forceinline__ float lo_bf(unsigned u){ return __uint_as_float(u<<16); }
__device__ __forceinline__ float hi_bf(unsigned u){ return __uint_as_float(u & 0xFFFF0000u); }
__device__ __forceinline__ float silu_f(float x){ return x / (1.f + __expf(-x)); }
__device__ __forceinline__ float ldsrc(const void* src, int i, int bf){
  return bf ? bf2f(((const u16*)src)[i]) : ((const float*)src)[i];
}
__device__ __forceinline__ unsigned packh2(float a, float b){
  return (unsigned)__half_as_ushort(__float2half(a)) |
         ((unsigned)__half_as_ushort(__float2half(b)) << 16);
}
__device__ __forceinline__ __half2 u2h2(unsigned u){ return __builtin_bit_cast(__half2, u); }

// ------------------------------------------------------------ dtype detect
__global__ void k_detect(const u16* __restrict__ rd, int* __restrict__ flag){
  if (threadIdx.x == 0 && blockIdx.x == 0){
    int ok = 1;
    for (int i = 0; i < 128; i++){
      float v = bf2f(rd[2*i]);
      if (!(v > 0.01f && v < 4.0f)) { ok = 0; break; }
    }
    *flag = ok;   // 1 = inputs bf16, 0 = fp32
  }
}

// ------------------------------------------- split helper: [L][K][N] -> [L][N][K] hi/lo
__device__ __forceinline__ void splitw(const void* src, u16* bh, u16* bl,
                                       int i, int K, int Ncol, int bf){
  int kn = K*Ncol; int l = i/kn; int r = i - l*kn; int k = r/Ncol; int n = r - k*Ncol;
  float w = ldsrc(src, i, bf);
  u16 h = f2bf(w);
  size_t o = (size_t)l*kn + (size_t)n*K + k;
  bh[o] = h; bl[o] = f2bf(w - bf2f(h));
}

// -------------------------------------- fused preamble (weights + edges + node init)
__global__ __launch_bounds__(256) void k_prep(
    const void* mb1, const void* mb2, const void* b1, const void* b2,
    const void* rw,  const void* rb,
    const void* mw1, const void* mw2, const void* w1, const void* w2,
    const void* Uw,  const void* Vw,
    const void* dist, const void* dirv, const int* __restrict__ idxj,
    const int* __restrict__ atoms, const void* __restrict__ emb,
    float* c_mb1, float* c_mb2, float* c_b1, float* c_b2,
    unsigned* rwp2,                 // [L][11][3F]
    u16* mw1h, u16* mw1l, u16* mw2h, u16* mw2l, u16* w1h, u16* w1l,
    u16* w2h, u16* w2l, u16* uvh, u16* uvl,
    uint4* edata,                   // [E][4]
    float* s, u16* s_h, u16* s_l,
    u16* p0h, u16* p0l, u16* bufA16, u16* bufB16,
    const int* __restrict__ flag){
  int i = blockIdx.x*256 + threadIdx.x;
  int bf = *flag;
  const int S0=NLAYER*F, S1=NLAYER*F3, S2=NLAYER*F, S3=NLAYER*F3;
  const int S4=NLAYER*11*F3;
  const int S5=NLAYER*F*F, S6=NLAYER*F*F3, S7=NLAYER*2*F*F, S8=NLAYER*F*F3, S9=NLAYER*256*F;
  if (i < S0){ c_mb1[i]=ldsrc(mb1,i,bf); return; } i-=S0;
  if (i < S1){ c_mb2[i]=ldsrc(mb2,i,bf); return; } i-=S1;
  if (i < S2){ c_b1[i] =ldsrc(b1, i,bf); return; } i-=S2;
  if (i < S3){ c_b2[i] =ldsrc(b2, i,bf); return; } i-=S3;
  if (i < S4){
    int l = i/(11*F3); int r = i - l*(11*F3); int r2 = r/F3; int col = r - r2*F3;
    float w0, w1v;
    if (r2 < 10){
      w0  = ldsrc(rw, (l*RBF + 2*r2  )*F3 + col, bf);
      w1v = ldsrc(rw, (l*RBF + 2*r2+1)*F3 + col, bf);
    } else {
      w0  = ldsrc(rb, l*F3 + col, bf);
      w1v = 0.f;
    }
    rwp2[i] = packh2(w0, w1v);
    return;
  } i-=S4;
  if (i < S5){ splitw(mw1, mw1h, mw1l, i, F,   F,  bf); return; } i-=S5;
  if (i < S6){ splitw(mw2, mw2h, mw2l, i, F,   F3, bf); return; } i-=S6;
  if (i < S7){ splitw(w1,  w1h,  w1l,  i, 2*F, F,  bf); return; } i-=S7;
  if (i < S8){ splitw(w2,  w2h,  w2l,  i, F,   F3, bf); return; } i-=S8;
  if (i < S9){
    int l=i/(256*F); int r=i-l*(256*F); int n=r>>7; int k=r&127;
    int si=(l*F+k)*F+(n&127);
    float w = ldsrc((n<128)?Uw:Vw, si, bf);
    u16 h=f2bf(w); uvh[i]=h; uvl[i]=f2bf(w-bf2f(h));
    return;
  } i-=S9;
  if (i < NEDGE){
    int e = i;
    float d = ldsrc(dist, e, bf);
    float cut = 0.5f*(cosf(PI_F*d*(1.f/3.f)) + 1.0f);
    float ic = cut/d;
    unsigned o[16];
    #pragma unroll
    for (int r2=0;r2<10;r2++){
      float s0 = sinf((2*r2+1)*PI_F*d*(1.f/3.f))*ic;
      float s1 = sinf((2*r2+2)*PI_F*d*(1.f/3.f))*ic;
      o[r2] = packh2(s0, s1);
    }
    o[10] = packh2(cut, 0.f);
    o[11] = __float_as_uint(ldsrc(dirv, e*3+0, bf));
    o[12] = __float_as_uint(ldsrc(dirv, e*3+1, bf));
    o[13] = __float_as_uint(ldsrc(dirv, e*3+2, bf));
    o[14] = (unsigned)idxj[e];
    o[15] = 0;
    uint4* dst = edata + (size_t)e*4;
    dst[0] = make_uint4(o[0],o[1],o[2],o[3]);
    dst[1] = make_uint4(o[4],o[5],o[6],o[7]);
    dst[2] = make_uint4(o[8],o[9],o[10],o[11]);
    dst[3] = make_uint4(o[12],o[13],o[14],o[15]);
    return;
  } i-=NEDGE;
  if (i < NF){                      // node init
    int n = i >> 7, f = i & 127;
    float sv = ldsrc(emb, atoms[n]*F + f, bf);
    s[i] = sv;
    u16 hb = f2bf(sv); s_h[i] = hb; s_l[i] = f2bf(sv - bf2f(hb));
    p0h[i]=0; p0h[NF+i]=0; p0h[2*(size_t)NF+i]=0;
    p0l[i]=0; p0l[NF+i]=0; p0l[2*(size_t)NF+i]=0;
    bufA16[(size_t)i*4+2]=0; bufA16[(size_t)i*4+3]=0;
    bufB16[(size_t)i*2+1]=0;
  }
}
#define PREP_TOTAL (NLAYER*(F+F3+F+F3+11*F3+F*F+F*F3+2*F*F+F*F3+256*F) + NEDGE + NF)

// --------------------------------- fused message MLP: phi = silu(s@mw1+b1)@mw2+b2
// 16 rows per block (grid 512). h lives only in LDS. Output packed into bufA/bufB.
__global__ __launch_bounds__(256) void k_msg(const u16* __restrict__ s_h,
                                             const u16* __restrict__ s_l,
                                             const u16* __restrict__ w1h_,  // [128][128]
                                             const u16* __restrict__ w1l_,
                                             const u16* __restrict__ w2h_,  // [384][128]
                                             const u16* __restrict__ w2l_,
                                             const float* __restrict__ b1,
                                             const float* __restrict__ b2,
                                             u16* __restrict__ bufA16,
                                             u16* __restrict__ bufB16){
  __shared__ u16 Ah[16*136], Al[16*136];
  __shared__ u16 Hh[16*136], Hl[16*136];
  __shared__ u16 Bh[64*136], Bl[64*136];
  int t = threadIdx.x, lane = t&63, w = t>>6;
  int row0 = blockIdx.x<<4;
  int l15 = lane&15, q8 = (lane>>4)<<3, qrow = (lane>>4)<<2;

  // stage A (s planes): 16x128 x2 planes = 512 uint4, 2/thread
  #pragma unroll
  for (int q=0;q<2;q++){
    int id = t + 256*q; int pl = id>>8, rem = id&255, r = rem>>4, c = (rem&15)<<3;
    *(uint4*)((pl?Al:Ah)+r*136+c) = *(const uint4*)((pl?s_l:s_h) + (size_t)(row0+r)*F + c);
  }

  // phase 1: h = silu(s@mw1+b1), col-groups of 64
  for (int cg=0;cg<2;cg++){
    __syncthreads();
    #pragma unroll
    for (int q=0;q<8;q++){   // B: 64x128 x2 = 2048 uint4
      int id = t + 256*q; int pl = id>>10, rem = id&1023, r = rem>>4, c = (rem&15)<<3;
      *(uint4*)((pl?Bl:Bh)+r*136+c) = *(const uint4*)((pl?w1l_:w1h_) + (size_t)(cg*64+r)*F + c);
    }
    __syncthreads();
    f32x4 acc; acc[0]=0;acc[1]=0;acc[2]=0;acc[3]=0;
    #pragma unroll
    for (int k0=0;k0<F;k0+=32){
      bf16x8 a_h = *(const bf16x8*)&Ah[l15*136 + k0 + q8];
      bf16x8 a_l = *(const bf16x8*)&Al[l15*136 + k0 + q8];
      bf16x8 b_h = *(const bf16x8*)&Bh[(w*16+l15)*136 + k0 + q8];
      bf16x8 b_l = *(const bf16x8*)&Bl[(w*16+l15)*136 + k0 + q8];
      acc = __builtin_amdgcn_mfma_f32_16x16x32_bf16(a_h, b_h, acc, 0,0,0);
      acc = __builtin_amdgcn_mfma_f32_16x16x32_bf16(a_h, b_l, acc, 0,0,0);
      acc = __builtin_amdgcn_mfma_f32_16x16x32_bf16(a_l, b_h, acc, 0,0,0);
    }
    int col = cg*64 + w*16 + l15;
    float bb = b1[col];
    #pragma unroll
    for (int r=0;r<4;r++){
      float val = silu_f(acc[r] + bb);
      u16 hb = f2bf(val);
      Hh[(qrow+r)*136 + col] = hb;
      Hl[(qrow+r)*136 + col] = f2bf(val - bf2f(hb));
    }
  }

  // phase 2: phi = h@mw2+b2, col-groups of 64, packed output
  for (int cg=0;cg<6;cg++){
    __syncthreads();
    #pragma unroll
    for (int q=0;q<8;q++){
      int id = t + 256*q; int pl = id>>10, rem = id&1023, r = rem>>4, c = (rem&15)<<3;
      *(uint4*)((pl?Bl:Bh)+r*136+c) = *(const uint4*)((pl?w2l_:w2h_) + (size_t)(cg*64+r)*F + c);
    }
    __syncthreads();
    f32x4 acc; acc[0]=0;acc[1]=0;acc[2]=0;acc[3]=0;
    #pragma unroll
    for (int k0=0;k0<F;k0+=32){
      bf16x8 a_h = *(const bf16x8*)&Hh[l15*136 + k0 + q8];
      bf16x8 a_l = *(const bf16x8*)&Hl[l15*136 + k0 + q8];
      bf16x8 b_h = *(const bf16x8*)&Bh[(w*16+l15)*136 + k0 + q8];
      bf16x8 b_l = *(const bf16x8*)&Bl[(w*16+l15)*136 + k0 + q8];
      acc = __builtin_amdgcn_mfma_f32_16x16x32_bf16(a_h, b_h, acc, 0,0,0);
      acc = __builtin_amdgcn_mfma_f32_16x16x32_bf16(a_h, b_l, acc, 0,0,0);
      acc = __builtin_amdgcn_mfma_f32_16x16x32_bf16(a_l, b_h, acc, 0,0,0);
    }
    int gc = cg*64 + w*16 + l15;
    float bb = b2[gc];
    #pragma unroll
    for (int r=0;r<4;r++){
      int grow = row0 + qrow + r;
      u16 v = f2bf(acc[r] + bb);
      size_t rowo = (size_t)grow*F;
      if (gc < F)        bufA16[(rowo + gc)*4 + 0]     = v;  // phi_vv
      else if (gc < 2*F) bufA16[(rowo + gc - F)*4 + 1] = v;  // phi_ss
      else               bufB16[(rowo + gc - 2*F)*2]   = v;  // phi_vs
    }
  }
}

// ------------------------------------------------- fused message aggregation
__global__ __launch_bounds__(256) void k_agg(const uint4* __restrict__ ed_g,
                                             const uint2* __restrict__ bufA,
                                             const unsigned* __restrict__ bufB,
                                             const unsigned* __restrict__ rwp2,  // [11][3F]
                                             const u16* __restrict__ vi_h,
                                             const u16* __restrict__ vi_l,
                                             u16* __restrict__ vo_h,
                                             u16* __restrict__ vo_l,
                                             float* __restrict__ s,
                                             u16* __restrict__ s_h,
                                             u16* __restrict__ s_l){
  __shared__ uint4 ed4[128];        // 2 nodes x 16 edges x 64B
  int t = threadIdx.x;
  int half = t >> 7, f = t & 127;

  __half2 rw2[3][11];
  #pragma unroll
  for (int r2=0;r2<11;r2++){
    rw2[0][r2] = u2h2(rwp2[r2*F3 + f]);
    rw2[1][r2] = u2h2(rwp2[r2*F3 + F + f]);
    rw2[2][r2] = u2h2(rwp2[r2*F3 + 2*F + f]);
  }

  int nA = blockIdx.x * 2;
  if (t < 128) ed4[t] = ed_g[(size_t)nA*64 + t];
  __syncthreads();

  int n = nA + half;
  int base = half*64;
  float ds=0.f, dv0=0.f, dv1=0.f, dv2=0.f;

  int j0 = (int)(ed4[base+3].z & (N_NODES-1));
  uint2    pa = bufA[(size_t)j0*F + f];
  unsigned pb = bufB[(size_t)j0*F + f];
  for (int el=0;el<DEG;el++){
    uint2 cpa = pa; unsigned cpb = pb;
    if (el+1 < DEG){
      int j1 = (int)(ed4[base+(el+1)*4+3].z & (N_NODES-1));
      pa = bufA[(size_t)j1*F + f];
      pb = bufB[(size_t)j1*F + f];
    }
    uint4 q0 = ed4[base+el*4+0];
    uint4 q1 = ed4[base+el*4+1];
    uint4 q2 = ed4[base+el*4+2];
    uint4 q3 = ed4[base+el*4+3];
    __half2 rc[11] = {u2h2(q0.x),u2h2(q0.y),u2h2(q0.z),u2h2(q0.w),
                      u2h2(q1.x),u2h2(q1.y),u2h2(q1.z),u2h2(q1.w),
                      u2h2(q2.x),u2h2(q2.y),u2h2(q2.z)};
    __half2 a0 = __hmul2(rc[0], rw2[0][0]);
    __half2 a1 = __hmul2(rc[0], rw2[1][0]);
    __half2 a2 = __hmul2(rc[0], rw2[2][0]);
    #pragma unroll
    for (int r2=1;r2<11;r2++){
      a0 = __hfma2(rc[r2], rw2[0][r2], a0);
      a1 = __hfma2(rc[r2], rw2[1][r2], a1);
      a2 = __hfma2(rc[r2], rw2[2][r2], a2);
    }
    float Wvv = __low2float(a0) + __high2float(a0);
    float Wss = __low2float(a1) + __high2float(a1);
    float Wvs = __low2float(a2) + __high2float(a2);
    float pvv = Wvv*lo_bf(cpa.x), pss = Wss*hi_bf(cpa.x), pvs = Wvs*lo_bf(cpb);
    ds += pss;
    dv0 += lo_bf(cpa.y)*pvv + pvs*__uint_as_float(q2.w);
    dv1 += hi_bf(cpa.y)*pvv + pvs*__uint_as_float(q3.x);
    dv2 += hi_bf(cpb)  *pvv + pvs*__uint_as_float(q3.y);
  }
  size_t i = (size_t)n*F + f;
  const float inv = 1.f/DEG;
  float sv = s[i] + ds*inv;
  s[i] = sv;
  { u16 hb = f2bf(sv); s_h[i] = hb; s_l[i] = f2bf(sv - bf2f(hb)); }
  float o0 = bf2f(vi_h[i])            + bf2f(vi_l[i])            + dv0*inv;
  float o1 = bf2f(vi_h[NF+i])         + bf2f(vi_l[NF+i])         + dv1*inv;
  float o2 = bf2f(vi_h[2*(size_t)NF+i]) + bf2f(vi_l[2*(size_t)NF+i]) + dv2*inv;
  u16 h0=f2bf(o0), h1=f2bf(o1), h2=f2bf(o2);
  vo_h[i]=h0; vo_h[NF+i]=h1; vo_h[2*(size_t)NF+i]=h2;
  vo_l[i]=f2bf(o0-bf2f(h0)); vo_l[NF+i]=f2bf(o1-bf2f(h1)); vo_l[2*(size_t)NF+i]=f2bf(o2-bf2f(h2));
}

// ------------------------------------ fused Uv/Vv GEMM + dot/norm, 32x64 tile
__global__ __launch_bounds__(256) void k_uvdot(const u16* __restrict__ voh,
                                               const u16* __restrict__ vol,
                                               const u16* __restrict__ Bh_g,   // uvW [256][128]
                                               const u16* __restrict__ Bl_g,
                                               const float* __restrict__ s,
                                               float* __restrict__ uvF,        // [3][N][F]
                                               float* __restrict__ dot,
                                               u16* __restrict__ ai_h,
                                               u16* __restrict__ ai_l){
  __shared__ u16 Ah[32*40], Al[32*40], BUh[64*40], BUl[64*40], BVh[64*40], BVl[64*40]; // 25.6KB
  int t = threadIdx.x;
  int row0 = blockIdx.y<<5, c0 = blockIdx.x<<6;
  int lane = t&63, w = t>>6;
  int qr = (w>>1)<<4, qc = (w&1)<<5;
  int l15 = lane&15, q8 = (lane>>4)<<3;
  int qrow = (lane>>4)<<2;
  int ap = t>>7, arem = t&127, ar = arem>>2, ac = (arem&3)<<3;
  f32x4 dA[2], nA2[2];
  dA[0][0]=0;dA[0][1]=0;dA[0][2]=0;dA[0][3]=0; dA[1]=dA[0];
  nA2[0]=dA[0]; nA2[1]=dA[0];

  for (int c=0;c<3;c++){
    f32x4 aU[2], aV[2];
    aU[0][0]=0;aU[0][1]=0;aU[0][2]=0;aU[0][3]=0; aU[1]=aU[0];
    aV[0]=aU[0]; aV[1]=aU[0];
    const u16* Asrc = (ap ? vol : voh) + (size_t)c*NF + (size_t)(row0+ar)*F + ac;
    u16* Adst = (ap ? Al : Ah) + ar*40 + ac;
    for (int k0=0;k0<F;k0+=32){
      *(uint4*)Adst = *(const uint4*)(Asrc + k0);
      #pragma unroll
      for (int q=0;q<4;q++){
        int idx = t + 256*q;
        int bp = idx>>8, rem = idx&255, br = rem>>2, bc = (rem&3)<<3;
        int grow = ((bp>>1) ? 128 : 0) + c0 + br;            // U rows then V rows
        const u16* Bsrc = ((bp&1) ? Bl_g : Bh_g) + (size_t)grow*F + k0 + bc;
        u16* Bdst;
        if (bp==0) Bdst = BUh; else if (bp==1) Bdst = BUl; else if (bp==2) Bdst = BVh; else Bdst = BVl;
        *(uint4*)(Bdst + br*40 + bc) = *(const uint4*)Bsrc;
      }
      __syncthreads();
      bf16x8 a_h = *(const bf16x8*)&Ah[(qr+l15)*40 + q8];
      bf16x8 a_l = *(const bf16x8*)&Al[(qr+l15)*40 + q8];
      #pragma unroll
      for (int nt=0;nt<2;nt++){
        int off = (qc+nt*16+l15)*40 + q8;
        bf16x8 bu_h = *(const bf16x8*)&BUh[off];
        bf16x8 bu_l = *(const bf16x8*)&BUl[off];
        bf16x8 bv_h = *(const bf16x8*)&BVh[off];
        bf16x8 bv_l = *(const bf16x8*)&BVl[off];
        aU[nt] = __builtin_amdgcn_mfma_f32_16x16x32_bf16(a_h, bu_h, aU[nt], 0,0,0);
        aU[nt] = __builtin_amdgcn_mfma_f32_16x16x32_bf16(a_h, bu_l, aU[nt], 0,0,0);
        aU[nt] = __builtin_amdgcn_mfma_f32_16x16x32_bf16(a_l, bu_h, aU[nt], 0,0,0);
        aV[nt] = __builtin_amdgcn_mfma_f32_16x16x32_bf16(a_h, bv_h, aV[nt], 0,0,0);
        aV[nt] = __builtin_amdgcn_mfma_f32_16x16x32_bf16(a_h, bv_l, aV[nt], 0,0,0);
        aV[nt] = __builtin_amdgcn_mfma_f32_16x16x32_bf16(a_l, bv_h, aV[nt], 0,0,0);
      }
      __syncthreads();
    }
    #pragma unroll
    for (int nt=0;nt<2;nt++){
      int gcol = c0 + qc + nt*16 + l15;
      #pragma unroll
      for (int r=0;r<4;r++){
        int grow = row0 + qr + qrow + r;
        float u = aU[nt][r], v = aV[nt][r];
        dA[nt][r] += u*v;
        nA2[nt][r] += v*v;
        uvF[(size_t)c*NF + (size_t)grow*F + gcol] = u;
      }
    }
  }
  #pragma unroll
  for (int nt=0;nt<2;nt++){
    int gcol = c0 + qc + nt*16 + l15;
    #pragma unroll
    for (int r=0;r<4;r++){
      int grow = row0 + qr + qrow + r;
      dot[(size_t)grow*F + gcol] = dA[nt][r];
      float vn = sqrtf(nA2[nt][r]);
      float sv = s[(size_t)grow*F + gcol];
      size_t b = (size_t)grow*256 + gcol;
      u16 h0 = f2bf(vn), h1 = f2bf(sv);
      ai_h[b] = h0;     ai_l[b] = f2bf(vn - bf2f(h0));
      ai_h[b+128] = h1; ai_l[b+128] = f2bf(sv - bf2f(h1));
    }
  }
}

// --------------- fused update MLP + apply: a = silu(ai@w1+b1)@w2+b2; apply epilogue
// 16 rows per block (grid 512). h and a live only in LDS.
__global__ __launch_bounds__(256) void k_upd(const u16* __restrict__ ai_h,
                                             const u16* __restrict__ ai_l,
                                             const u16* __restrict__ w1h_,  // [128][256]
                                             const u16* __restrict__ w1l_,
                                             const u16* __restrict__ w2h_,  // [384][128]
                                             const u16* __restrict__ w2l_,
                                             const float* __restrict__ b1,
                                             const float* __restrict__ b2,
                                             const float* __restrict__ dot,
                                             const float* __restrict__ uvF,
                                             float* __restrict__ s,
                                             u16* __restrict__ s_h,
                                             u16* __restrict__ s_l,
                                             u16* __restrict__ v_h,
                                             u16* __restrict__ v_l,
                                             u16* __restrict__ bufA16,
                                             u16* __restrict__ bufB16,
                                             float* __restrict__ out){
  __shared__ u16 Ah[16*264], Al[16*264];     // ai, K=256 resident
  __shared__ u16 Hh[16*136], Hl[16*136];
  __shared__ u16 Bh[64*136], Bl[64*136];
  __shared__ __half aLDS[16*392];
  int t = threadIdx.x, lane = t&63, w = t>>6;
  int row0 = blockIdx.x<<4;
  int l15 = lane&15, q8 = (lane>>4)<<3, qrow = (lane>>4)<<2;

  // stage A (ai planes): 16x256 x2 = 1024 uint4, 4/thread
  #pragma unroll
  for (int q=0;q<4;q++){
    int id = t + 256*q; int pl = id>>9, rem = id&511, r = rem>>5, c = (rem&31)<<3;
    *(uint4*)((pl?Al:Ah)+r*264+c) = *(const uint4*)((pl?ai_l:ai_h) + (size_t)(row0+r)*256 + c);
  }

  // phase 1: h = silu(ai@w1+b1), col-groups of 64, K=256 in 64-k chunks
  for (int cg=0;cg<2;cg++){
    f32x4 acc; acc[0]=0;acc[1]=0;acc[2]=0;acc[3]=0;
    for (int kc=0;kc<4;kc++){
      __syncthreads();
      #pragma unroll
      for (int q=0;q<4;q++){   // B chunk 64 cols x 64 k x2 = 1024 uint4
        int id = t + 256*q; int pl = id>>9, rem = id&511, r = rem>>3, c = (rem&7)<<3;
        *(uint4*)((pl?Bl:Bh)+r*136+c) =
            *(const uint4*)((pl?w1l_:w1h_) + (size_t)(cg*64+r)*256 + kc*64 + c);
      }
      __syncthreads();
      #pragma unroll
      for (int ks=0;ks<64;ks+=32){
        bf16x8 a_h = *(const bf16x8*)&Ah[l15*264 + kc*64 + ks + q8];
        bf16x8 a_l = *(const bf16x8*)&Al[l15*264 + kc*64 + ks + q8];
        bf16x8 b_h = *(const bf16x8*)&Bh[(w*16+l15)*136 + ks + q8];
        bf16x8 b_l = *(const bf16x8*)&Bl[(w*16+l15)*136 + ks + q8];
        acc = __builtin_amdgcn_mfma_f32_16x16x32_bf16(a_h, b_h, acc, 0,0,0);
        acc = __builtin_amdgcn_mfma_f32_16x16x32_bf16(a_h, b_l, acc, 0,0,0);
        acc = __builtin_amdgcn_mfma_f32_16x16x32_bf16(a_l, b_h, acc, 0,0,0);
      }
    }
    int col = cg*64 + w*16 + l15;
    float bb = b1[col];
    #pragma unroll
    for (int r=0;r<4;r++){
      float val = silu_f(acc[r] + bb);
      u16 hb = f2bf(val);
      Hh[(qrow+r)*136 + col] = hb;
      Hl[(qrow+r)*136 + col] = f2bf(val - bf2f(hb));
    }
  }

  // phase 2: a = h@w2+b2 -> aLDS (fp16)
  for (int cg=0;cg<6;cg++){
    __syncthreads();
    #pragma unroll
    for (int q=0;q<8;q++){
      int id = t + 256*q; int pl = id>>10, rem = id&1023, r = rem>>4, c = (rem&15)<<3;
      *(uint4*)((pl?Bl:Bh)+r*136+c) = *(const uint4*)((pl?w2l_:w2h_) + (size_t)(cg*64+r)*F + c);
    }
    __syncthreads();
    f32x4 acc; acc[0]=0;acc[1]=0;acc[2]=0;acc[3]=0;
    #pragma unroll
    for (int k0=0;k0<F;k0+=32){
      bf16x8 a_h = *(const bf16x8*)&Hh[l15*136 + k0 + q8];
      bf16x8 a_l = *(const bf16x8*)&Hl[l15*136 + k0 + q8];
      bf16x8 b_h = *(const bf16x8*)&Bh[(w*16+l15)*136 + k0 + q8];
      bf16x8 b_l = *(const bf16x8*)&Bl[(w*16+l15)*136 + k0 + q8];
      acc = __builtin_amdgcn_mfma_f32_16x16x32_bf16(a_h, b_h, acc, 0,0,0);
      acc = __builtin_amdgcn_mfma_f32_16x16x32_bf16(a_h, b_l, acc, 0,0,0);
      acc = __builtin_amdgcn_mfma_f32_16x16x32_bf16(a_l, b_h, acc, 0,0,0);
    }
    int gc = cg*64 + w*16 + l15;
    float bb = b2[gc];
    #pragma unroll
    for (int r=0;r<4;r++)
      aLDS[(qrow+r)*392 + gc] = __float2half(acc[r] + bb);
  }
  __syncthreads();

  // apply epilogue: 16x128 elems / 256 thr = 8 rows per thread
  int f = t & 127, rh = (t>>7)*8;
  #pragma unroll
  for (int e=0;e<8;e++){
    int r = rh + e;
    int grow = row0 + r;
    size_t i = (size_t)grow*F + f;
    float avv = __half2float(aLDS[r*392 + f]);
    float asv = __half2float(aLDS[r*392 + F + f]);
    float ass = __half2float(aLDS[r*392 + 2*F + f]);
    float sv = s[i] + ass + asv*dot[i];
    s[i] = sv;
    u16 hb = f2bf(sv); s_h[i] = hb; s_l[i] = f2bf(sv - bf2f(hb));
    float nv0 = bf2f(v_h[i])              + bf2f(v_l[i])              + uvF[i]*avv;
    float nv1 = bf2f(v_h[NF+i])           + bf2f(v_l[NF+i])           + uvF[NF+i]*avv;
    float nv2 = bf2f(v_h[2*(size_t)NF+i]) + bf2f(v_l[2*(size_t)NF+i]) + uvF[2*(size_t)NF+i]*avv;
    u16 h0=f2bf(nv0), h1=f2bf(nv1), h2=f2bf(nv2);
    v_h[i]=h0; v_h[NF+i]=h1; v_h[2*(size_t)NF+i]=h2;
    v_l[i]=f2bf(nv0-bf2f(h0)); v_l[NF+i]=f2bf(nv1-bf2f(h1)); v_l[2*(size_t)NF+i]=f2bf(nv2-bf2f(h2));
    bufA16[(size_t)i*4+2] = h0; bufA16[(size_t)i*4+3] = h1;
    bufB16[(size_t)i*2+1] = h2;
    if (out){
      out[i] = sv;
      out[NF + (size_t)i*3 + 0] = nv0;
      out[NF + (size_t)i*3 + 1] = nv1;
      out[NF + (size_t)i*3 + 2] = nv2;
    }
  }
}

// ------------------------------------------------------------------ launch
extern "C" void kernel_launch(void* const* d_in, const int* in_sizes, int n_in,
                              void* d_out, int out_size, void* d_ws, size_t ws_size,
                              hipStream_t stream) {
  const int* atoms   = (const int*)d_in[0];
  const int* idxj    = (const int*)d_in[2];

  float* W = (float*)d_ws;
  size_t off = 64;
  int* flag = (int*)d_ws;
  #define ALLOCF(name, cnt) float* name = W+off; off += (((cnt)+63)&~(size_t)63)
  #define ALLOCU(name, cnt) u16* name = (u16*)(W+off); off += ((((cnt)+1)/2+63)&~(size_t)63)
  ALLOCF(c_mb1, NLAYER*F);
  ALLOCF(c_mb2, NLAYER*F3);
  ALLOCF(c_b1,  NLAYER*F);
  ALLOCF(c_b2,  NLAYER*F3);
  unsigned* c_rwp2 = (unsigned*)(W+off); off += ((NLAYER*11*F3+63)&~(size_t)63);
  uint4* edata = (uint4*)(W+off); off += (size_t)NEDGE*16;  // E x 64B = E*16 floats
  ALLOCU(w_mw1h, NLAYER*F*F);   ALLOCU(w_mw1l, NLAYER*F*F);
  ALLOCU(w_mw2h, NLAYER*F*F3);  ALLOCU(w_mw2l, NLAYER*F*F3);
  ALLOCU(w_uvh,  NLAYER*256*F); ALLOCU(w_uvl,  NLAYER*256*F);
  ALLOCU(w_w1h,  NLAYER*F*256); ALLOCU(w_w1l,  NLAYER*F*256);
  ALLOCU(w_w2h,  NLAYER*F*F3);  ALLOCU(w_w2l,  NLAYER*F*F3);
  uint2* bufA = (uint2*)(W+off); off += (size_t)2*NF;       // NF x 8B
  unsigned* bufB = (unsigned*)(W+off); off += (size_t)NF;   // NF x 4B
  ALLOCU(p0h, (size_t)3*NF); ALLOCU(p0l, (size_t)3*NF);
  ALLOCU(p1h, (size_t)3*NF); ALLOCU(p1l, (size_t)3*NF);
  ALLOCU(s_h,  NF); ALLOCU(s_l,  NF);
  ALLOCU(ai_h, (size_t)2*NF); ALLOCU(ai_l, (size_t)2*NF);
  ALLOCF(s,    NF);
  ALLOCF(uvF,  (size_t)3*NF);
  ALLOCF(dotb, NF);

  k_detect<<<1, 64, 0, stream>>>((const u16*)d_in[4], flag);
  k_prep<<<(PREP_TOTAL+255)/256, 256, 0, stream>>>(
      d_in[7], d_in[9], d_in[15], d_in[17],
      d_in[10], d_in[11],
      d_in[6], d_in[8], d_in[14], d_in[16],
      d_in[12], d_in[13],
      d_in[4], d_in[3], idxj,
      atoms, d_in[5],
      c_mb1, c_mb2, c_b1, c_b2, c_rwp2,
      w_mw1h, w_mw1l, w_mw2h, w_mw2l, w_w1h, w_w1l,
      w_w2h, w_w2l, w_uvh, w_uvl, edata,
      s, s_h, s_l, p0h, p0l, (u16*)bufA, (u16*)bufB, flag);

  for (int l=0; l<NLAYER; l++){
    u16* vih = (l & 1) ? p1h : p0h;
    u16* vil = (l & 1) ? p1l : p0l;
    u16* voh = (l & 1) ? p0h : p1h;
    u16* vol = (l & 1) ? p0l : p1l;
    // ---- message block: fused MLP + phi pack ----
    k_msg<<<N_NODES/16, 256, 0, stream>>>(
        s_h, s_l,
        w_mw1h + (size_t)l*F*F,  w_mw1l + (size_t)l*F*F,
        w_mw2h + (size_t)l*F*F3, w_mw2l + (size_t)l*F*F3,
        c_mb1 + (size_t)l*F, c_mb2 + (size_t)l*F3,
        (u16*)bufA, (u16*)bufB);
    k_agg<<<N_NODES/2, 256, 0, stream>>>(
        edata, bufA, bufB, c_rwp2 + (size_t)l*11*F3,
        vih, vil, voh, vol, s, s_h, s_l);
    // ---- update block ----
    k_uvdot<<<dim3(2, N_NODES/32), 256, 0, stream>>>(
        voh, vol, w_uvh + (size_t)l*256*F, w_uvl + (size_t)l*256*F,
        s, uvF, dotb, ai_h, ai_l);
    k_upd<<<N_NODES/16, 256, 0, stream>>>(
        ai_h, ai_l,
        w_w1h + (size_t)l*F*256, w_w1l + (size_t)l*F*256,
        w_w2h + (size_t)l*F*F3,  w_w2l + (size_t)l*F*F3,
        c_b1 + (size_t)l*F, c_b2 + (size_t)l*F3,
        dotb, uvF, s, s_h, s_l, voh, vol,
        (u16*)bufA, (u16*)bufB,
        (l == NLAYER-1) ? (float*)d_out : nullptr);
  }
}